// Round 2
// baseline (40977.954 us; speedup 1.0000x reference)
//
#include <hip/hip_runtime.h>
#include <hip/hip_bf16.h>
#include <stdint.h>

#define B_ 256
#define T_ 150
#define S_ 151
#define E_ 512
#define H_ 8
#define L_ 6
#define FF_ 2048
#define M_ (B_*S_)   // 38656 = 302*128

typedef __hip_bfloat16 bf16;
typedef __bf16 bf16x8 __attribute__((ext_vector_type(8)));
typedef float f32x4 __attribute__((ext_vector_type(4)));

__device__ inline void unpack8(uint4 u, float* f) {
    union { uint32_t u; float f; } c;
    c.u = u.x << 16;         f[0] = c.f;
    c.u = u.x & 0xffff0000u; f[1] = c.f;
    c.u = u.y << 16;         f[2] = c.f;
    c.u = u.y & 0xffff0000u; f[3] = c.f;
    c.u = u.z << 16;         f[4] = c.f;
    c.u = u.z & 0xffff0000u; f[5] = c.f;
    c.u = u.w << 16;         f[6] = c.f;
    c.u = u.w & 0xffff0000u; f[7] = c.f;
}

// ---------------- weight transpose f32[K][N] -> bf16[N][K], batched over L ----
__global__ __launch_bounds__(256)
void transpose_cast_kernel(const float* __restrict__ src, bf16* __restrict__ dst,
                           int K, int N) {
    __shared__ float tile[64][65];
    int l = blockIdx.z;
    const float* s = src + (size_t)l * K * N;
    bf16* d = dst + (size_t)l * K * N;
    int bk = blockIdx.x * 64, bn = blockIdx.y * 64;
    int col = threadIdx.x & 63, rg = threadIdx.x >> 6;
#pragma unroll
    for (int i = 0; i < 16; ++i) {
        int r = i * 4 + rg;
        tile[r][col] = s[(size_t)(bk + r) * N + bn + col];
    }
    __syncthreads();
#pragma unroll
    for (int i = 0; i < 16; ++i) {
        int r = i * 4 + rg;
        d[(size_t)(bn + r) * K + bk + col] = __float2bfloat16(tile[col][r]);
    }
}

// ---------------- token embedding + pos + cls -> x32, xbf ---------------------
__global__ __launch_bounds__(256)
void embed_kernel(const int* __restrict__ tt, const int* __restrict__ dec_idx,
                  const float* __restrict__ action_val, const float* __restrict__ dis_val,
                  const float* __restrict__ v_val,
                  const float* __restrict__ action_W, const float* __restrict__ action_b,
                  const float* __restrict__ dis_W, const float* __restrict__ dis_b,
                  const float* __restrict__ v_W, const float* __restrict__ v_b,
                  const float* __restrict__ dec_emb, const float* __restrict__ pos,
                  const float* __restrict__ cls,
                  float* __restrict__ x32, bf16* __restrict__ xbf) {
    int bs = blockIdx.x;
    int b = bs / S_, s = bs - b * S_;
    size_t out = (size_t)bs * E_;
    for (int e = threadIdx.x; e < E_; e += 256) {
        float val;
        if (s == 0) {
            val = cls[e];
        } else {
            int t = s - 1;
            int ty = tt[b * T_ + t];
            if (ty == 0) {
                val = action_val[b * T_ + t] * action_W[e] + action_b[e];
            } else if (ty == 1) {
                val = dis_b[e] + v_b[e];
#pragma unroll
                for (int i = 0; i < 10; ++i) val += dis_val[(b * T_ + t) * 10 + i] * dis_W[i * E_ + e];
#pragma unroll
                for (int i = 0; i < 3; ++i)  val += v_val[(b * T_ + t) * 3 + i] * v_W[i * E_ + e];
            } else {
                val = dec_emb[(size_t)dec_idx[b * T_ + t] * E_ + e];
            }
            val += pos[(size_t)t * E_ + e];
        }
        x32[out + e] = val;
        xbf[out + e] = __float2bfloat16(val);
    }
}

// ---------------- bf16 MFMA GEMM: C = A[rows,K] * B[K,N] (+bias,+res,relu) ---
// Bt is B transposed: [N][K] bf16. 128x128 tile, BK=64, 4 waves (2x2), each
// wave 64x64 = 4x4 frags of 16x16x32. LDS tiles XOR-swizzled (chunk ^= row&7).
// MODE: 1 = bf16 out, relu(acc+bias)  |  2 = f32 out, acc+bias+res
//       3 = bf16 out, acc+bias
template<int MODE>
__global__ __launch_bounds__(256, 2)
void gemm_kernel(const bf16* __restrict__ A, const bf16* __restrict__ Bt,
                 const float* __restrict__ bias, const float* __restrict__ res,
                 float* __restrict__ Cf, bf16* __restrict__ Cb,
                 int N, int K) {
    __shared__ alignas(16) bf16 As[128][64];
    __shared__ alignas(16) bf16 Bs[128][64];
    const int tid = threadIdx.x;
    const int wave = tid >> 6, lane = tid & 63;
    const int m0 = blockIdx.x * 128, n0 = blockIdx.y * 128;
    const int wm = (wave >> 1) * 64, wn = (wave & 1) * 64;
    const int l15 = lane & 15, lg = lane >> 4;

    f32x4 acc[4][4] = {};

    for (int k0 = 0; k0 < K; k0 += 64) {
        // stage (reg -> LDS, swizzled)
#pragma unroll
        for (int i = 0; i < 4; ++i) {
            int chunk = i * 256 + tid;      // 0..1023 16B chunks
            int row = chunk >> 3, c = chunk & 7;
            int csw = c ^ (row & 7);
            uint4 av = *(const uint4*)(A + (size_t)(m0 + row) * K + k0 + c * 8);
            *(uint4*)((char*)&As[0][0] + row * 128 + csw * 16) = av;
            uint4 bv = *(const uint4*)(Bt + (size_t)(n0 + row) * K + k0 + c * 8);
            *(uint4*)((char*)&Bs[0][0] + row * 128 + csw * 16) = bv;
        }
        __syncthreads();
#pragma unroll
        for (int kf = 0; kf < 2; ++kf) {
            bf16x8 af[4], bfr[4];
#pragma unroll
            for (int mf = 0; mf < 4; ++mf) {
                int row = wm + mf * 16 + l15;
                int csw = (kf * 4 + lg) ^ (row & 7);
                af[mf] = *(const bf16x8*)((const char*)&As[0][0] + row * 128 + csw * 16);
            }
#pragma unroll
            for (int nf = 0; nf < 4; ++nf) {
                int row = wn + nf * 16 + l15;
                int csw = (kf * 4 + lg) ^ (row & 7);
                bfr[nf] = *(const bf16x8*)((const char*)&Bs[0][0] + row * 128 + csw * 16);
            }
#pragma unroll
            for (int mf = 0; mf < 4; ++mf)
#pragma unroll
                for (int nf = 0; nf < 4; ++nf)
                    acc[mf][nf] = __builtin_amdgcn_mfma_f32_16x16x32_bf16(
                        af[mf], bfr[nf], acc[mf][nf], 0, 0, 0);
        }
        __syncthreads();
    }
    // epilogue: C/D layout col = lane&15, row = (lane>>4)*4 + j
#pragma unroll
    for (int nf = 0; nf < 4; ++nf) {
        int col = n0 + wn + nf * 16 + l15;
        float bv = bias[col];
#pragma unroll
        for (int mf = 0; mf < 4; ++mf) {
#pragma unroll
            for (int j = 0; j < 4; ++j) {
                int row = m0 + wm + mf * 16 + lg * 4 + j;
                size_t idx = (size_t)row * N + col;
                float x = acc[mf][nf][j] + bv;
                if (MODE == 2) { x += res[idx]; Cf[idx] = x; }
                else if (MODE == 1) { x = fmaxf(x, 0.f); Cb[idx] = __float2bfloat16(x); }
                else { Cb[idx] = __float2bfloat16(x); }
            }
        }
    }
}

// ---------------- attention: one block per (b,h), vector math ----------------
// qkv: [nb*S,1536] bf16 for a chunk of nb batches; mask offset likewise.
__global__ __launch_bounds__(256, 2)
void attn_kernel(const bf16* __restrict__ qkv, const int* __restrict__ mask,
                 bf16* __restrict__ obf) {
    __shared__ alignas(16) bf16 Kb[151][64];     // swizzled rows
    __shared__ alignas(16) bf16 Qb[151][64];     // swizzled rows
    __shared__ alignas(16) bf16 Vt[64][168];     // V transposed, padded stride
    __shared__ alignas(16) bf16 pbuf[4][4][152]; // per-wave P rows
    __shared__ bf16 biasv[192];

    int bh = blockIdx.x;
    int b = bh >> 3, h = bh & 7;
    int tid = threadIdx.x, wave = tid >> 6, lane = tid & 63;
    const size_t base = (size_t)b * S_ * 1536 + h * 64;

    for (int idx = tid; idx < 151 * 64; idx += 256) {
        int r = idx >> 6, d = idx & 63;
        int csw = (d >> 3) ^ (r & 7);
        Kb[r][csw * 8 + (d & 7)] = qkv[base + (size_t)r * 1536 + 512 + d];
        Qb[r][csw * 8 + (d & 7)] = qkv[base + (size_t)r * 1536 + d];
        Vt[d][r] = qkv[base + (size_t)r * 1536 + 1024 + d];
    }
    if (tid < 64) Vt[tid][151] = __float2bfloat16(0.f);
    if (tid < 192) {
        float bv;
        if (tid == 0) bv = 0.f;
        else if (tid <= 150) bv = (mask[b * T_ + tid - 1] != 0) ? 0.f : -1e9f;
        else bv = -1e30f;
        biasv[tid] = __float2bfloat16(bv);
    }
    __syncthreads();

    const float scale = 0.125f;  // 1/sqrt(64)
    for (int g = wave; g < 38; g += 4) {
        int r0 = g * 4;
        float s[3][4] = {};
#pragma unroll
        for (int c = 0; c < 8; ++c) {
            float qv[4][8];
#pragma unroll
            for (int r = 0; r < 4; ++r) {
                int row = r0 + r;
                if (row < 151) {
                    int csw = c ^ (row & 7);
                    uint4 u = *(const uint4*)((const char*)&Qb[0][0] + row * 128 + csw * 16);
                    unpack8(u, qv[r]);
                } else {
#pragma unroll
                    for (int e = 0; e < 8; ++e) qv[r][e] = 0.f;
                }
            }
#pragma unroll
            for (int jj = 0; jj < 3; ++jj) {
                int j = lane + jj * 64;
                if (j < 151) {
                    int csw = c ^ (j & 7);
                    uint4 u = *(const uint4*)((const char*)&Kb[0][0] + j * 128 + csw * 16);
                    float kf[8]; unpack8(u, kf);
#pragma unroll
                    for (int e = 0; e < 8; ++e)
#pragma unroll
                        for (int r = 0; r < 4; ++r)
                            s[jj][r] += qv[r][e] * kf[e];
                }
            }
        }
#pragma unroll
        for (int jj = 0; jj < 3; ++jj) {
            int j = lane + jj * 64;
            float bj = __bfloat162float(biasv[j]);
#pragma unroll
            for (int r = 0; r < 4; ++r) s[jj][r] = s[jj][r] * scale + bj;
        }
        float inv[4];
#pragma unroll
        for (int r = 0; r < 4; ++r) {
            float m = fmaxf(fmaxf(s[0][r], s[1][r]), s[2][r]);
#pragma unroll
            for (int off = 1; off < 64; off <<= 1) m = fmaxf(m, __shfl_xor(m, off));
            float p0 = __expf(s[0][r] - m);
            float p1 = __expf(s[1][r] - m);
            float p2 = __expf(s[2][r] - m);
            float sum = p0 + p1 + p2;
#pragma unroll
            for (int off = 1; off < 64; off <<= 1) sum += __shfl_xor(sum, off);
            inv[r] = 1.f / sum;
            pbuf[wave][r][lane] = __float2bfloat16(p0);
            pbuf[wave][r][lane + 64] = __float2bfloat16(p1);
            if (lane + 128 < 152) pbuf[wave][r][lane + 128] = __float2bfloat16(p2);
        }
        // phase 2: o[d] = sum_j p[j] * V[j][d], lane = d
        int d = lane;
        float o[4] = {0.f, 0.f, 0.f, 0.f};
        for (int j0 = 0; j0 < 152; j0 += 8) {
            uint4 vv = *(const uint4*)((const char*)&Vt[0][0] + (d * 168 + j0) * 2);
            float vf[8]; unpack8(vv, vf);
#pragma unroll
            for (int r = 0; r < 4; ++r) {
                uint4 pu = *(const uint4*)&pbuf[wave][r][j0];
                float pf[8]; unpack8(pu, pf);
#pragma unroll
                for (int e = 0; e < 8; ++e) o[r] += pf[e] * vf[e];
            }
        }
#pragma unroll
        for (int r = 0; r < 4; ++r) {
            int row = r0 + r;
            if (row < 151)
                obf[((size_t)(b * S_ + row)) * E_ + h * 64 + d] = __float2bfloat16(o[r] * inv[r]);
        }
    }
}

// ---------------- LayerNorm over E=512, one block per row --------------------
__global__ __launch_bounds__(256)
void ln_kernel(const float* __restrict__ in, const float* __restrict__ gw,
               const float* __restrict__ bw, float* __restrict__ x32,
               bf16* __restrict__ xbf) {
    int row = blockIdx.x;
    const float* p = in + (size_t)row * E_;
    int t = threadIdx.x;
    int wave = t >> 6, lane = t & 63;
    float v0 = p[t], v1 = p[t + 256];
    float s = v0 + v1;
#pragma unroll
    for (int off = 1; off < 64; off <<= 1) s += __shfl_xor(s, off);
    __shared__ float ws1[4], ws2[4];
    if (lane == 0) ws1[wave] = s;
    __syncthreads();
    float mean = (ws1[0] + ws1[1] + ws1[2] + ws1[3]) * (1.0f / 512.0f);
    float d0 = v0 - mean, d1 = v1 - mean;
    float q = d0 * d0 + d1 * d1;
#pragma unroll
    for (int off = 1; off < 64; off <<= 1) q += __shfl_xor(q, off);
    if (lane == 0) ws2[wave] = q;
    __syncthreads();
    float var = (ws2[0] + ws2[1] + ws2[2] + ws2[3]) * (1.0f / 512.0f);
    float rstd = rsqrtf(var + 1e-5f);
    float y0 = d0 * rstd * gw[t] + bw[t];
    float y1 = d1 * rstd * gw[t + 256] + bw[t + 256];
    size_t o = (size_t)row * E_;
    x32[o + t] = y0;       x32[o + t + 256] = y1;
    xbf[o + t] = __float2bfloat16(y0);
    xbf[o + t + 256] = __float2bfloat16(y1);
}

// ---------------- final: out[b,:] = x32[b*S + 0, :] --------------------------
__global__ __launch_bounds__(256)
void out_kernel(const float* __restrict__ x32, float* __restrict__ out) {
    int i = blockIdx.x * 256 + threadIdx.x;
    int b = i >> 9, e = i & 511;
    out[i] = x32[(size_t)b * S_ * E_ + e];
}

extern "C" void kernel_launch(void* const* d_in, const int* in_sizes, int n_in,
                              void* d_out, int out_size, void* d_ws, size_t ws_size,
                              hipStream_t stream) {
    (void)in_sizes; (void)n_in; (void)out_size; (void)ws_size;
    const int*   token_type = (const int*)d_in[0];
    const int*   mask       = (const int*)d_in[1];
    const int*   dec_idx    = (const int*)d_in[2];
    const float* action_val = (const float*)d_in[3];
    const float* dis_val    = (const float*)d_in[4];
    const float* v_val      = (const float*)d_in[5];
    const float* action_W   = (const float*)d_in[6];
    const float* action_b   = (const float*)d_in[7];
    const float* dis_W      = (const float*)d_in[8];
    const float* dis_b      = (const float*)d_in[9];
    const float* v_W        = (const float*)d_in[10];
    const float* v_b        = (const float*)d_in[11];
    const float* dec_emb    = (const float*)d_in[12];
    const float* pos        = (const float*)d_in[13];
    const float* cls        = (const float*)d_in[14];
    const float* qkv_W      = (const float*)d_in[15];
    const float* qkv_b      = (const float*)d_in[16];
    const float* out_W      = (const float*)d_in[17];
    const float* out_b      = (const float*)d_in[18];
    const float* ln1_g      = (const float*)d_in[19];
    const float* ln1_b      = (const float*)d_in[20];
    const float* ff1_W      = (const float*)d_in[21];
    const float* ff1_b      = (const float*)d_in[22];
    const float* ff2_W      = (const float*)d_in[23];
    const float* ff2_b      = (const float*)d_in[24];
    const float* ln2_g      = (const float*)d_in[25];
    const float* ln2_b      = (const float*)d_in[26];

    // ---- workspace layout: ~225 MB total ------------------------------------
    char* ws = (char*)d_ws;
    size_t off = 0;
    auto alloc = [&](size_t bytes) {
        char* p = ws + off;
        off += (bytes + 255) & ~(size_t)255;
        return p;
    };
    bf16* qkvT = (bf16*)alloc((size_t)L_ * 1536 * 512 * 2);  //  9.4 MB
    bf16* outT = (bf16*)alloc((size_t)L_ * 512 * 512 * 2);   //  3.1 MB
    bf16* ff1T = (bf16*)alloc((size_t)L_ * 2048 * 512 * 2);  // 12.6 MB
    bf16* ff2T = (bf16*)alloc((size_t)L_ * 512 * 2048 * 2);  // 12.6 MB
    float* x32 = (float*)alloc((size_t)M_ * E_ * 4);         // 79.2 MB residual (f32)
    bf16*  xbf = (bf16*)alloc((size_t)M_ * E_ * 2);          // 39.6 MB x(bf16) / attn-out
    char*  arena = alloc((size_t)M_ * E_ * 4);               // 79.2 MB shared scratch
    // arena roles (sequential lifetimes):
    //   qkv half-chunk:  19328*1536*2 = 59.4 MB
    //   proj t32 (full): 38656*512*4  = 79.2 MB
    //   ff chunk: hbf_c <=9728*2048*2 = 39.85 MB  +  t32_c <=9728*512*4 = 19.9 MB

    dim3 blk(256);
    transpose_cast_kernel<<<dim3(8, 24, L_), blk, 0, stream>>>(qkv_W, qkvT, 512, 1536);
    transpose_cast_kernel<<<dim3(8, 8,  L_), blk, 0, stream>>>(out_W, outT, 512, 512);
    transpose_cast_kernel<<<dim3(8, 32, L_), blk, 0, stream>>>(ff1_W, ff1T, 512, 2048);
    transpose_cast_kernel<<<dim3(32, 8, L_), blk, 0, stream>>>(ff2_W, ff2T, 2048, 512);

    embed_kernel<<<dim3(M_), blk, 0, stream>>>(token_type, dec_idx, action_val, dis_val, v_val,
        action_W, action_b, dis_W, dis_b, v_W, v_b, dec_emb, pos, cls, x32, xbf);

    const int HALF_ROWS = 19328;                 // 128 batches * 151
    const size_t HOFF = (size_t)9728 * FF_ * 2;  // hbf_c bytes (76 tiles)
    const int ffTiles[4] = {76, 76, 76, 74};
    const int ffBase[4]  = {0, 9728, 19456, 29184};

    for (int l = 0; l < L_; ++l) {
        const bf16* qT = qkvT + (size_t)l * 1536 * 512;
        const bf16* oT = outT + (size_t)l * 512 * 512;
        const bf16* f1 = ff1T + (size_t)l * 2048 * 512;
        const bf16* f2 = ff2T + (size_t)l * 512 * 2048;

        // QKV + attention, chunked over 2 batch-halves (arena = qkv chunk)
        for (int c = 0; c < 2; ++c) {
            gemm_kernel<3><<<dim3(151, 12), blk, 0, stream>>>(
                xbf + (size_t)c * HALF_ROWS * E_, qT, qkv_b + l * 1536, nullptr,
                nullptr, (bf16*)arena, 1536, 512);
            attn_kernel<<<dim3(128 * H_), blk, 0, stream>>>(
                (const bf16*)arena, mask + c * 128 * T_,
                xbf + (size_t)c * HALF_ROWS * E_);   // attn-out overwrites xbf
        }
        // proj + residual -> t32 (arena), then LN1 -> x32/xbf
        gemm_kernel<2><<<dim3(302, 4), blk, 0, stream>>>(
            xbf, oT, out_b + l * 512, x32, (float*)arena, nullptr, 512, 512);
        ln_kernel<<<dim3(M_), blk, 0, stream>>>(
            (const float*)arena, ln1_g + l * 512, ln1_b + l * 512, x32, xbf);
        // FF, chunked over 4 row-groups (arena = hbf_c | t32_c)
        for (int c = 0; c < 4; ++c) {
            int rb = ffBase[c], nt = ffTiles[c];
            gemm_kernel<1><<<dim3(nt, 16), blk, 0, stream>>>(
                xbf + (size_t)rb * E_, f1, ff1_b + l * 2048, nullptr,
                nullptr, (bf16*)arena, 2048, 512);
            gemm_kernel<2><<<dim3(nt, 4), blk, 0, stream>>>(
                (const bf16*)arena, f2, ff2_b + l * 512, x32 + (size_t)rb * E_,
                (float*)(arena + HOFF), nullptr, 512, 2048);
            ln_kernel<<<dim3(nt * 128), blk, 0, stream>>>(
                (const float*)(arena + HOFF), ln2_g + l * 512, ln2_b + l * 512,
                x32 + (size_t)rb * E_, xbf + (size_t)rb * E_);
        }
    }
    out_kernel<<<dim3(B_ * E_ / 256), blk, 0, stream>>>(x32, (float*)d_out);
}

// Round 3
// 3670.793 us; speedup vs baseline: 11.1632x; 11.1632x over previous
//
#include <hip/hip_runtime.h>
#include <hip/hip_bf16.h>
#include <stdint.h>

#define B_ 256
#define T_ 150
#define S_ 151
#define E_ 512
#define H_ 8
#define L_ 6
#define FF_ 2048
#define M_ (B_*S_)   // 38656 = 302*128

typedef __hip_bfloat16 bf16;
typedef __bf16 bf16x8 __attribute__((ext_vector_type(8)));
typedef float f32x4 __attribute__((ext_vector_type(4)));
typedef unsigned short u16x8 __attribute__((ext_vector_type(8)));

// ---------------- weight transpose f32[K][N] -> bf16[N][K], batched over L ----
__global__ __launch_bounds__(256)
void transpose_cast_kernel(const float* __restrict__ src, bf16* __restrict__ dst,
                           int K, int N) {
    __shared__ float tile[64][65];
    int l = blockIdx.z;
    const float* s = src + (size_t)l * K * N;
    bf16* d = dst + (size_t)l * K * N;
    int bk = blockIdx.x * 64, bn = blockIdx.y * 64;
    int col = threadIdx.x & 63, rg = threadIdx.x >> 6;
#pragma unroll
    for (int i = 0; i < 16; ++i) {
        int r = i * 4 + rg;
        tile[r][col] = s[(size_t)(bk + r) * N + bn + col];
    }
    __syncthreads();
#pragma unroll
    for (int i = 0; i < 16; ++i) {
        int r = i * 4 + rg;
        d[(size_t)(bn + r) * K + bk + col] = __float2bfloat16(tile[col][r]);
    }
}

// ---------------- token embedding + pos + cls -> x32, xbf ---------------------
__global__ __launch_bounds__(256)
void embed_kernel(const int* __restrict__ tt, const int* __restrict__ dec_idx,
                  const float* __restrict__ action_val, const float* __restrict__ dis_val,
                  const float* __restrict__ v_val,
                  const float* __restrict__ action_W, const float* __restrict__ action_b,
                  const float* __restrict__ dis_W, const float* __restrict__ dis_b,
                  const float* __restrict__ v_W, const float* __restrict__ v_b,
                  const float* __restrict__ dec_emb, const float* __restrict__ pos,
                  const float* __restrict__ cls,
                  float* __restrict__ x32, bf16* __restrict__ xbf) {
    int bs = blockIdx.x;
    int b = bs / S_, s = bs - b * S_;
    size_t out = (size_t)bs * E_;
    for (int e = threadIdx.x; e < E_; e += 256) {
        float val;
        if (s == 0) {
            val = cls[e];
        } else {
            int t = s - 1;
            int ty = tt[b * T_ + t];
            if (ty == 0) {
                val = action_val[b * T_ + t] * action_W[e] + action_b[e];
            } else if (ty == 1) {
                val = dis_b[e] + v_b[e];
#pragma unroll
                for (int i = 0; i < 10; ++i) val += dis_val[(b * T_ + t) * 10 + i] * dis_W[i * E_ + e];
#pragma unroll
                for (int i = 0; i < 3; ++i)  val += v_val[(b * T_ + t) * 3 + i] * v_W[i * E_ + e];
            } else {
                val = dec_emb[(size_t)dec_idx[b * T_ + t] * E_ + e];
            }
            val += pos[(size_t)t * E_ + e];
        }
        x32[out + e] = val;
        xbf[out + e] = __float2bfloat16(val);
    }
}

// ---------------- bf16 MFMA GEMM: C = A[rows,K] * B[K,N] (+bias,+res,relu) ---
// Bt is B transposed: [N][K] bf16. 128x128 tile, BK=64, 4 waves (2x2), each
// wave 64x64 = 4x4 frags of 16x16x32. LDS tiles XOR-swizzled (chunk ^= row&7).
// MODE: 1 = bf16 out, relu(acc+bias)  |  2 = f32 out, acc+bias+res
//       3 = bf16 out, acc+bias
template<int MODE>
__global__ __launch_bounds__(256, 2)
void gemm_kernel(const bf16* __restrict__ A, const bf16* __restrict__ Bt,
                 const float* __restrict__ bias, const float* __restrict__ res,
                 float* __restrict__ Cf, bf16* __restrict__ Cb,
                 int N, int K) {
    __shared__ alignas(16) bf16 As[128][64];
    __shared__ alignas(16) bf16 Bs[128][64];
    const int tid = threadIdx.x;
    const int wave = tid >> 6, lane = tid & 63;
    const int m0 = blockIdx.x * 128, n0 = blockIdx.y * 128;
    const int wm = (wave >> 1) * 64, wn = (wave & 1) * 64;
    const int l15 = lane & 15, lg = lane >> 4;

    f32x4 acc[4][4] = {};

    for (int k0 = 0; k0 < K; k0 += 64) {
        // stage (reg -> LDS, swizzled)
#pragma unroll
        for (int i = 0; i < 4; ++i) {
            int chunk = i * 256 + tid;      // 0..1023 16B chunks
            int row = chunk >> 3, c = chunk & 7;
            int csw = c ^ (row & 7);
            uint4 av = *(const uint4*)(A + (size_t)(m0 + row) * K + k0 + c * 8);
            *(uint4*)((char*)&As[0][0] + row * 128 + csw * 16) = av;
            uint4 bv = *(const uint4*)(Bt + (size_t)(n0 + row) * K + k0 + c * 8);
            *(uint4*)((char*)&Bs[0][0] + row * 128 + csw * 16) = bv;
        }
        __syncthreads();
#pragma unroll
        for (int kf = 0; kf < 2; ++kf) {
            bf16x8 af[4], bfr[4];
#pragma unroll
            for (int mf = 0; mf < 4; ++mf) {
                int row = wm + mf * 16 + l15;
                int csw = (kf * 4 + lg) ^ (row & 7);
                af[mf] = *(const bf16x8*)((const char*)&As[0][0] + row * 128 + csw * 16);
            }
#pragma unroll
            for (int nf = 0; nf < 4; ++nf) {
                int row = wn + nf * 16 + l15;
                int csw = (kf * 4 + lg) ^ (row & 7);
                bfr[nf] = *(const bf16x8*)((const char*)&Bs[0][0] + row * 128 + csw * 16);
            }
#pragma unroll
            for (int mf = 0; mf < 4; ++mf)
#pragma unroll
                for (int nf = 0; nf < 4; ++nf)
                    acc[mf][nf] = __builtin_amdgcn_mfma_f32_16x16x32_bf16(
                        af[mf], bfr[nf], acc[mf][nf], 0, 0, 0);
        }
        __syncthreads();
    }
    // epilogue: C/D layout col = lane&15, row = (lane>>4)*4 + j
#pragma unroll
    for (int nf = 0; nf < 4; ++nf) {
        int col = n0 + wn + nf * 16 + l15;
        float bv = bias[col];
#pragma unroll
        for (int mf = 0; mf < 4; ++mf) {
#pragma unroll
            for (int j = 0; j < 4; ++j) {
                int row = m0 + wm + mf * 16 + lg * 4 + j;
                size_t idx = (size_t)row * N + col;
                float x = acc[mf][nf][j] + bv;
                if (MODE == 2) { x += res[idx]; Cf[idx] = x; }
                else if (MODE == 1) { x = fmaxf(x, 0.f); Cb[idx] = __float2bfloat16(x); }
                else { Cb[idx] = __float2bfloat16(x); }
            }
        }
    }
}

// ---------------- attention: MFMA, one block per (b,h) ----------------------
// qkv: [nb*S,1536] bf16 chunk. S padded to 160 (10 m/n-tiles of 16).
// LDS union (64128 B): Kb[160][64] swz | QP = Q[160][64] swz then Pb[4][16][168]
// | Vt[64][168] | biasf[160]. No address-taken per-thread arrays anywhere.
#define VP_ 168
__global__ __launch_bounds__(256, 2)
void attn_kernel(const bf16* __restrict__ qkv, const int* __restrict__ mask,
                 bf16* __restrict__ obf) {
    __shared__ alignas(16) unsigned short ldsbuf[32064];
    unsigned short* Kb = ldsbuf;                       // 10240 u16
    unsigned short* QP = ldsbuf + 10240;               // 10752 u16 (Q 10240 / Pb 10752)
    unsigned short* Vt = ldsbuf + 10240 + 10752;       // 10752 u16, [64][168]
    float* biasf = (float*)(ldsbuf + 10240 + 10752 + 10752);  // 160 f32

    const int bh = blockIdx.x;
    const int b = bh >> 3, h = bh & 7;
    const int tid = threadIdx.x, w = tid >> 6, lane = tid & 63;
    const int l15 = lane & 15, lg = lane >> 4;
    const size_t base = (size_t)b * S_ * 1536 + h * 64;
    const unsigned short* qk16 = (const unsigned short*)qkv;

    // ---- stage K, Q (row-major, XOR-swizzled) and V (transposed) -----------
    for (int i = tid; i < 160 * 8; i += 256) {
        int r = i >> 3, c = i & 7;
        int csw = c ^ (r & 7);
        uint4 kz = make_uint4(0u, 0u, 0u, 0u), qz = kz;
        if (r < 151) {
            kz = *(const uint4*)(qk16 + base + (size_t)r * 1536 + 512 + c * 8);
            qz = *(const uint4*)(qk16 + base + (size_t)r * 1536 + c * 8);
        }
        *(uint4*)((char*)Kb + r * 128 + csw * 16) = kz;
        *(uint4*)((char*)QP + r * 128 + csw * 16) = qz;
    }
    for (int i = tid; i < 160 * 8; i += 256) {
        int n = i >> 3, c = i & 7;
        u16x8 vv = {0, 0, 0, 0, 0, 0, 0, 0};
        if (n < 151) vv = *(const u16x8*)(qk16 + base + (size_t)n * 1536 + 1024 + c * 8);
#pragma unroll
        for (int e = 0; e < 8; ++e) Vt[(c * 8 + e) * VP_ + n] = vv[e];
    }
    if (tid < 160) {
        float bv;
        if (tid == 0) bv = 0.f;
        else if (tid <= 150) bv = (mask[b * T_ + tid - 1] != 0) ? 0.f : -1e9f;
        else bv = -1e9f;
        biasf[tid] = bv;
    }
    __syncthreads();

    // ---- preload Q A-frags (3 m-tiles per wave: w, w+4, w+8) ---------------
    int r0 = w * 16 + l15;
    int r1 = r0 + 64;
    int r2 = r0 + 128; if (r2 > 159) r2 = 159;   // clamp (unused when mt>=10)
    bf16x8 q00 = *(const bf16x8*)((const char*)QP + r0 * 128 + ((lg)     ^ (r0 & 7)) * 16);
    bf16x8 q01 = *(const bf16x8*)((const char*)QP + r0 * 128 + ((4 + lg) ^ (r0 & 7)) * 16);
    bf16x8 q10 = *(const bf16x8*)((const char*)QP + r1 * 128 + ((lg)     ^ (r1 & 7)) * 16);
    bf16x8 q11 = *(const bf16x8*)((const char*)QP + r1 * 128 + ((4 + lg) ^ (r1 & 7)) * 16);
    bf16x8 q20 = *(const bf16x8*)((const char*)QP + r2 * 128 + ((lg)     ^ (r2 & 7)) * 16);
    bf16x8 q21 = *(const bf16x8*)((const char*)QP + r2 * 128 + ((4 + lg) ^ (r2 & 7)) * 16);
    // bias per column (col = nt*16 + l15), hoisted to regs
    float bc0 = biasf[l15],       bc1 = biasf[16 + l15],  bc2 = biasf[32 + l15];
    float bc3 = biasf[48 + l15],  bc4 = biasf[64 + l15],  bc5 = biasf[80 + l15];
    float bc6 = biasf[96 + l15],  bc7 = biasf[112 + l15], bc8 = biasf[128 + l15];
    float bc9 = biasf[144 + l15];
    __syncthreads();   // QP now becomes the per-wave P buffer

    bf16* Pw = (bf16*)(QP + w * 16 * VP_);
    const float scale = 0.125f;

#pragma unroll
    for (int mi = 0; mi < 3; ++mi) {
        int mt = w + mi * 4;
        if (mt < 10) {
            bf16x8 qk0 = (mi == 0) ? q00 : (mi == 1) ? q10 : q20;
            bf16x8 qk1 = (mi == 0) ? q01 : (mi == 1) ? q11 : q21;
            // ---- QK^T: 10 n-tiles ------------------------------------------
            f32x4 sc[10] = {};
#pragma unroll
            for (int nt = 0; nt < 10; ++nt) {
                int kr = nt * 16 + l15;
                bf16x8 kb0 = *(const bf16x8*)((const char*)Kb + kr * 128 + ((lg)     ^ (kr & 7)) * 16);
                bf16x8 kb1 = *(const bf16x8*)((const char*)Kb + kr * 128 + ((4 + lg) ^ (kr & 7)) * 16);
                sc[nt] = __builtin_amdgcn_mfma_f32_16x16x32_bf16(qk0, kb0, sc[nt], 0, 0, 0);
                sc[nt] = __builtin_amdgcn_mfma_f32_16x16x32_bf16(qk1, kb1, sc[nt], 0, 0, 0);
            }
            // ---- scale + bias, row max (rows = lg*4+j, cols = nt*16+l15) ---
            float m0r = -3e38f, m1r = -3e38f, m2r = -3e38f, m3r = -3e38f;
#pragma unroll
            for (int nt = 0; nt < 10; ++nt) {
                float bv = (nt == 0) ? bc0 : (nt == 1) ? bc1 : (nt == 2) ? bc2 :
                           (nt == 3) ? bc3 : (nt == 4) ? bc4 : (nt == 5) ? bc5 :
                           (nt == 6) ? bc6 : (nt == 7) ? bc7 : (nt == 8) ? bc8 : bc9;
                sc[nt][0] = sc[nt][0] * scale + bv;  m0r = fmaxf(m0r, sc[nt][0]);
                sc[nt][1] = sc[nt][1] * scale + bv;  m1r = fmaxf(m1r, sc[nt][1]);
                sc[nt][2] = sc[nt][2] * scale + bv;  m2r = fmaxf(m2r, sc[nt][2]);
                sc[nt][3] = sc[nt][3] * scale + bv;  m3r = fmaxf(m3r, sc[nt][3]);
            }
#pragma unroll
            for (int off = 1; off < 16; off <<= 1) {
                m0r = fmaxf(m0r, __shfl_xor(m0r, off));
                m1r = fmaxf(m1r, __shfl_xor(m1r, off));
                m2r = fmaxf(m2r, __shfl_xor(m2r, off));
                m3r = fmaxf(m3r, __shfl_xor(m3r, off));
            }
            // ---- exp + row sum ---------------------------------------------
            float s0 = 0.f, s1 = 0.f, s2 = 0.f, s3 = 0.f;
#pragma unroll
            for (int nt = 0; nt < 10; ++nt) {
                sc[nt][0] = __expf(sc[nt][0] - m0r);  s0 += sc[nt][0];
                sc[nt][1] = __expf(sc[nt][1] - m1r);  s1 += sc[nt][1];
                sc[nt][2] = __expf(sc[nt][2] - m2r);  s2 += sc[nt][2];
                sc[nt][3] = __expf(sc[nt][3] - m3r);  s3 += sc[nt][3];
            }
#pragma unroll
            for (int off = 1; off < 16; off <<= 1) {
                s0 += __shfl_xor(s0, off);
                s1 += __shfl_xor(s1, off);
                s2 += __shfl_xor(s2, off);
                s3 += __shfl_xor(s3, off);
            }
            s0 = 1.f / s0; s1 = 1.f / s1; s2 = 1.f / s2; s3 = 1.f / s3;
            // ---- P -> LDS (bf16, per-wave buffer) --------------------------
#pragma unroll
            for (int nt = 0; nt < 10; ++nt) {
                int cb = nt * 16 + l15;
                Pw[(lg * 4 + 0) * VP_ + cb] = __float2bfloat16(sc[nt][0]);
                Pw[(lg * 4 + 1) * VP_ + cb] = __float2bfloat16(sc[nt][1]);
                Pw[(lg * 4 + 2) * VP_ + cb] = __float2bfloat16(sc[nt][2]);
                Pw[(lg * 4 + 3) * VP_ + cb] = __float2bfloat16(sc[nt][3]);
            }
            // ---- PV: O[16 x 64] = P[16 x 160] * V[160 x 64] ----------------
            f32x4 oc[4] = {};
#pragma unroll
            for (int nc = 0; nc < 5; ++nc) {
                bf16x8 pa = *(const bf16x8*)((const unsigned short*)Pw + l15 * VP_ + nc * 32 + lg * 8);
#pragma unroll
                for (int dt = 0; dt < 4; ++dt) {
                    bf16x8 vb = *(const bf16x8*)(Vt + (dt * 16 + l15) * VP_ + nc * 32 + lg * 8);
                    oc[dt] = __builtin_amdgcn_mfma_f32_16x16x32_bf16(pa, vb, oc[dt], 0, 0, 0);
                }
            }
            // ---- write O (rows = mt*16 + lg*4 + j, cols = dt*16 + l15) -----
            int orow = mt * 16 + lg * 4;
#pragma unroll
            for (int dt = 0; dt < 4; ++dt) {
                int d = h * 64 + dt * 16 + l15;
                if (orow + 0 < 151) obf[((size_t)(b * S_ + orow + 0)) * E_ + d] = __float2bfloat16(oc[dt][0] * s0);
                if (orow + 1 < 151) obf[((size_t)(b * S_ + orow + 1)) * E_ + d] = __float2bfloat16(oc[dt][1] * s1);
                if (orow + 2 < 151) obf[((size_t)(b * S_ + orow + 2)) * E_ + d] = __float2bfloat16(oc[dt][2] * s2);
                if (orow + 3 < 151) obf[((size_t)(b * S_ + orow + 3)) * E_ + d] = __float2bfloat16(oc[dt][3] * s3);
            }
        }
    }
}

// ---------------- LayerNorm over E=512, one block per row --------------------
__global__ __launch_bounds__(256)
void ln_kernel(const float* __restrict__ in, const float* __restrict__ gw,
               const float* __restrict__ bw, float* __restrict__ x32,
               bf16* __restrict__ xbf) {
    int row = blockIdx.x;
    const float* p = in + (size_t)row * E_;
    int t = threadIdx.x;
    int wave = t >> 6, lane = t & 63;
    float v0 = p[t], v1 = p[t + 256];
    float s = v0 + v1;
#pragma unroll
    for (int off = 1; off < 64; off <<= 1) s += __shfl_xor(s, off);
    __shared__ float ws1[4], ws2[4];
    if (lane == 0) ws1[wave] = s;
    __syncthreads();
    float mean = (ws1[0] + ws1[1] + ws1[2] + ws1[3]) * (1.0f / 512.0f);
    float d0 = v0 - mean, d1 = v1 - mean;
    float q = d0 * d0 + d1 * d1;
#pragma unroll
    for (int off = 1; off < 64; off <<= 1) q += __shfl_xor(q, off);
    if (lane == 0) ws2[wave] = q;
    __syncthreads();
    float var = (ws2[0] + ws2[1] + ws2[2] + ws2[3]) * (1.0f / 512.0f);
    float rstd = rsqrtf(var + 1e-5f);
    float y0 = d0 * rstd * gw[t] + bw[t];
    float y1 = d1 * rstd * gw[t + 256] + bw[t + 256];
    size_t o = (size_t)row * E_;
    x32[o + t] = y0;       x32[o + t + 256] = y1;
    xbf[o + t] = __float2bfloat16(y0);
    xbf[o + t + 256] = __float2bfloat16(y1);
}

// ---------------- final: out[b,:] = x32[b*S + 0, :] --------------------------
__global__ __launch_bounds__(256)
void out_kernel(const float* __restrict__ x32, float* __restrict__ out) {
    int i = blockIdx.x * 256 + threadIdx.x;
    int b = i >> 9, e = i & 511;
    out[i] = x32[(size_t)b * S_ * E_ + e];
}

extern "C" void kernel_launch(void* const* d_in, const int* in_sizes, int n_in,
                              void* d_out, int out_size, void* d_ws, size_t ws_size,
                              hipStream_t stream) {
    (void)in_sizes; (void)n_in; (void)out_size; (void)ws_size;
    const int*   token_type = (const int*)d_in[0];
    const int*   mask       = (const int*)d_in[1];
    const int*   dec_idx    = (const int*)d_in[2];
    const float* action_val = (const float*)d_in[3];
    const float* dis_val    = (const float*)d_in[4];
    const float* v_val      = (const float*)d_in[5];
    const float* action_W   = (const float*)d_in[6];
    const float* action_b   = (const float*)d_in[7];
    const float* dis_W      = (const float*)d_in[8];
    const float* dis_b      = (const float*)d_in[9];
    const float* v_W        = (const float*)d_in[10];
    const float* v_b        = (const float*)d_in[11];
    const float* dec_emb    = (const float*)d_in[12];
    const float* pos        = (const float*)d_in[13];
    const float* cls        = (const float*)d_in[14];
    const float* qkv_W      = (const float*)d_in[15];
    const float* qkv_b      = (const float*)d_in[16];
    const float* out_W      = (const float*)d_in[17];
    const float* out_b      = (const float*)d_in[18];
    const float* ln1_g      = (const float*)d_in[19];
    const float* ln1_b      = (const float*)d_in[20];
    const float* ff1_W      = (const float*)d_in[21];
    const float* ff1_b      = (const float*)d_in[22];
    const float* ff2_W      = (const float*)d_in[23];
    const float* ff2_b      = (const float*)d_in[24];
    const float* ln2_g      = (const float*)d_in[25];
    const float* ln2_b      = (const float*)d_in[26];

    // ---- workspace layout: ~225 MB total ------------------------------------
    char* ws = (char*)d_ws;
    size_t off = 0;
    auto alloc = [&](size_t bytes) {
        char* p = ws + off;
        off += (bytes + 255) & ~(size_t)255;
        return p;
    };
    bf16* qkvT = (bf16*)alloc((size_t)L_ * 1536 * 512 * 2);  //  9.4 MB
    bf16* outT = (bf16*)alloc((size_t)L_ * 512 * 512 * 2);   //  3.1 MB
    bf16* ff1T = (bf16*)alloc((size_t)L_ * 2048 * 512 * 2);  // 12.6 MB
    bf16* ff2T = (bf16*)alloc((size_t)L_ * 512 * 2048 * 2);  // 12.6 MB
    float* x32 = (float*)alloc((size_t)M_ * E_ * 4);         // 79.2 MB residual (f32)
    bf16*  xbf = (bf16*)alloc((size_t)M_ * E_ * 2);          // 39.6 MB x(bf16) / attn-out
    char*  arena = alloc((size_t)M_ * E_ * 4);               // 79.2 MB shared scratch

    dim3 blk(256);
    transpose_cast_kernel<<<dim3(8, 24, L_), blk, 0, stream>>>(qkv_W, qkvT, 512, 1536);
    transpose_cast_kernel<<<dim3(8, 8,  L_), blk, 0, stream>>>(out_W, outT, 512, 512);
    transpose_cast_kernel<<<dim3(8, 32, L_), blk, 0, stream>>>(ff1_W, ff1T, 512, 2048);
    transpose_cast_kernel<<<dim3(32, 8, L_), blk, 0, stream>>>(ff2_W, ff2T, 2048, 512);

    embed_kernel<<<dim3(M_), blk, 0, stream>>>(token_type, dec_idx, action_val, dis_val, v_val,
        action_W, action_b, dis_W, dis_b, v_W, v_b, dec_emb, pos, cls, x32, xbf);

    const int HALF_ROWS = 19328;                 // 128 batches * 151
    const size_t HOFF = (size_t)9728 * FF_ * 2;  // hbf_c bytes (76 tiles)
    const int ffTiles[4] = {76, 76, 76, 74};
    const int ffBase[4]  = {0, 9728, 19456, 29184};

    for (int l = 0; l < L_; ++l) {
        const bf16* qT = qkvT + (size_t)l * 1536 * 512;
        const bf16* oT = outT + (size_t)l * 512 * 512;
        const bf16* f1 = ff1T + (size_t)l * 2048 * 512;
        const bf16* f2 = ff2T + (size_t)l * 512 * 2048;

        // QKV + attention, chunked over 2 batch-halves (arena = qkv chunk)
        for (int c = 0; c < 2; ++c) {
            gemm_kernel<3><<<dim3(151, 12), blk, 0, stream>>>(
                xbf + (size_t)c * HALF_ROWS * E_, qT, qkv_b + l * 1536, nullptr,
                nullptr, (bf16*)arena, 1536, 512);
            attn_kernel<<<dim3(128 * H_), blk, 0, stream>>>(
                (const bf16*)arena, mask + c * 128 * T_,
                xbf + (size_t)c * HALF_ROWS * E_);   // attn-out overwrites xbf
        }
        // proj + residual -> t32 (arena), then LN1 -> x32/xbf
        gemm_kernel<2><<<dim3(302, 4), blk, 0, stream>>>(
            xbf, oT, out_b + l * 512, x32, (float*)arena, nullptr, 512, 512);
        ln_kernel<<<dim3(M_), blk, 0, stream>>>(
            (const float*)arena, ln1_g + l * 512, ln1_b + l * 512, x32, xbf);
        // FF, chunked over 4 row-groups (arena = hbf_c | t32_c)
        for (int c = 0; c < 4; ++c) {
            int rb = ffBase[c], nt = ffTiles[c];
            gemm_kernel<1><<<dim3(nt, 16), blk, 0, stream>>>(
                xbf + (size_t)rb * E_, f1, ff1_b + l * 2048, nullptr,
                nullptr, (bf16*)arena, 2048, 512);
            gemm_kernel<2><<<dim3(nt, 4), blk, 0, stream>>>(
                (const bf16*)arena, f2, ff2_b + l * 512, x32 + (size_t)rb * E_,
                (float*)(arena + HOFF), nullptr, 512, 2048);
            ln_kernel<<<dim3(nt * 128), blk, 0, stream>>>(
                (const float*)(arena + HOFF), ln2_g + l * 512, ln2_b + l * 512,
                x32 + (size_t)rb * E_, xbf + (size_t)rb * E_);
        }
    }
    out_kernel<<<dim3(B_ * E_ / 256), blk, 0, stream>>>(x32, (float*)d_out);
}

// Round 4
// 3441.107 us; speedup vs baseline: 11.9084x; 1.0667x over previous
//
#include <hip/hip_runtime.h>
#include <hip/hip_bf16.h>
#include <stdint.h>

#define B_ 256
#define T_ 150
#define S_ 151
#define E_ 512
#define H_ 8
#define L_ 6
#define FF_ 2048
#define M_ (B_*S_)   // 38656 = 302*128

typedef __hip_bfloat16 bf16;
typedef __bf16 bf16x8 __attribute__((ext_vector_type(8)));
typedef float f32x4 __attribute__((ext_vector_type(4)));
typedef unsigned short u16x8 __attribute__((ext_vector_type(8)));

__device__ inline unsigned short f2b(float x) {
    union { __hip_bfloat16 h; unsigned short u; } c;
    c.h = __float2bfloat16(x);
    return c.u;
}
__device__ inline float b2f(unsigned short u) {
    union { uint32_t u; float f; } c;
    c.u = (uint32_t)u << 16;
    return c.f;
}

// ---------------- weight transpose f32[K][N] -> bf16[N][K], batched over L ----
__global__ __launch_bounds__(256)
void transpose_cast_kernel(const float* __restrict__ src, bf16* __restrict__ dst,
                           int K, int N) {
    __shared__ float tile[64][65];
    int l = blockIdx.z;
    const float* s = src + (size_t)l * K * N;
    bf16* d = dst + (size_t)l * K * N;
    int bk = blockIdx.x * 64, bn = blockIdx.y * 64;
    int col = threadIdx.x & 63, rg = threadIdx.x >> 6;
#pragma unroll
    for (int i = 0; i < 16; ++i) {
        int r = i * 4 + rg;
        tile[r][col] = s[(size_t)(bk + r) * N + bn + col];
    }
    __syncthreads();
#pragma unroll
    for (int i = 0; i < 16; ++i) {
        int r = i * 4 + rg;
        d[(size_t)(bn + r) * K + bk + col] = __float2bfloat16(tile[col][r]);
    }
}

// ---------------- token embedding + pos + cls -> x32, xbf (4 rows/block) -----
__global__ __launch_bounds__(256)
void embed_kernel(const int* __restrict__ tt, const int* __restrict__ dec_idx,
                  const float* __restrict__ action_val, const float* __restrict__ dis_val,
                  const float* __restrict__ v_val,
                  const float* __restrict__ action_W, const float* __restrict__ action_b,
                  const float* __restrict__ dis_W, const float* __restrict__ dis_b,
                  const float* __restrict__ v_W, const float* __restrict__ v_b,
                  const float* __restrict__ dec_emb, const float* __restrict__ pos,
                  const float* __restrict__ cls,
                  float* __restrict__ x32, bf16* __restrict__ xbf) {
    int lane = threadIdx.x & 63;
    int bs = blockIdx.x * 4 + (threadIdx.x >> 6);
    int b = bs / S_, s = bs - b * S_;
    int e0 = lane * 8;
    f32x4 v0, v1;
    if (s == 0) {
        v0 = *(const f32x4*)(cls + e0);
        v1 = *(const f32x4*)(cls + e0 + 4);
    } else {
        int t = s - 1;
        int ty = tt[b * T_ + t];
        if (ty == 0) {
            float av = action_val[b * T_ + t];
            f32x4 w0 = *(const f32x4*)(action_W + e0);
            f32x4 w1 = *(const f32x4*)(action_W + e0 + 4);
            f32x4 b0 = *(const f32x4*)(action_b + e0);
            f32x4 b1 = *(const f32x4*)(action_b + e0 + 4);
            v0 = w0 * av + b0;  v1 = w1 * av + b1;
        } else if (ty == 1) {
            v0 = *(const f32x4*)(dis_b + e0) + *(const f32x4*)(v_b + e0);
            v1 = *(const f32x4*)(dis_b + e0 + 4) + *(const f32x4*)(v_b + e0 + 4);
#pragma unroll
            for (int i = 0; i < 10; ++i) {
                float dv = dis_val[(b * T_ + t) * 10 + i];
                v0 += *(const f32x4*)(dis_W + i * E_ + e0) * dv;
                v1 += *(const f32x4*)(dis_W + i * E_ + e0 + 4) * dv;
            }
#pragma unroll
            for (int i = 0; i < 3; ++i) {
                float vv = v_val[(b * T_ + t) * 3 + i];
                v0 += *(const f32x4*)(v_W + i * E_ + e0) * vv;
                v1 += *(const f32x4*)(v_W + i * E_ + e0 + 4) * vv;
            }
        } else {
            const float* de = dec_emb + (size_t)dec_idx[b * T_ + t] * E_;
            v0 = *(const f32x4*)(de + e0);
            v1 = *(const f32x4*)(de + e0 + 4);
        }
        v0 += *(const f32x4*)(pos + (size_t)t * E_ + e0);
        v1 += *(const f32x4*)(pos + (size_t)t * E_ + e0 + 4);
    }
    size_t o = (size_t)bs * E_ + e0;
    *(f32x4*)(x32 + o) = v0;
    *(f32x4*)(x32 + o + 4) = v1;
    union { unsigned short s[8]; uint4 v; } pk;
    pk.s[0] = f2b(v0[0]); pk.s[1] = f2b(v0[1]); pk.s[2] = f2b(v0[2]); pk.s[3] = f2b(v0[3]);
    pk.s[4] = f2b(v1[0]); pk.s[5] = f2b(v1[1]); pk.s[6] = f2b(v1[2]); pk.s[7] = f2b(v1[3]);
    *(uint4*)((unsigned short*)xbf + o) = pk.v;
}

// ---------------- bf16 MFMA GEMM: C = A[rows,K] * Bt[N,K] (+bias[,relu]) -----
// 128x128 tile, BK=64, 4 waves (2x2), 4x4 frags of 16x16x32, XOR-swizzled LDS.
// XCD-chunked n-fastest tile mapping (bijective): bid%8 = XCD, contiguous wgid
// range per XCD so the A-panel working set stays in the XCD-private L2.
// MODE: 1 = relu(acc+bias) -> bf16 | 3 = acc+bias -> bf16
template<int MODE>
__global__ __launch_bounds__(256, 2)
void gemm_kernel(const bf16* __restrict__ A, const bf16* __restrict__ Bt,
                 const float* __restrict__ bias, bf16* __restrict__ Cb,
                 int N, int K) {
    __shared__ alignas(16) bf16 As[128][64];
    __shared__ alignas(16) bf16 Bs[128][64];
    const int tid = threadIdx.x;
    const int wave = tid >> 6, lane = tid & 63;
    const int nwg = gridDim.x, bid = blockIdx.x;
    const int Nt = N >> 7;
    const int q = nwg >> 3, r = nwg & 7;
    const int xcd = bid & 7, slot = bid >> 3;
    const int wgid = (xcd < r ? xcd * (q + 1) : r * (q + 1) + (xcd - r) * q) + slot;
    const int mt = wgid / Nt, ntl = wgid - mt * Nt;
    const int m0 = mt * 128, n0 = ntl * 128;
    const int wm = (wave >> 1) * 64, wn = (wave & 1) * 64;
    const int l15 = lane & 15, lg = lane >> 4;

    f32x4 acc[4][4] = {};

    for (int k0 = 0; k0 < K; k0 += 64) {
        // stage (reg -> LDS, swizzled)
#pragma unroll
        for (int i = 0; i < 4; ++i) {
            int chunk = i * 256 + tid;      // 0..1023 16B chunks
            int row = chunk >> 3, c = chunk & 7;
            int csw = c ^ (row & 7);
            uint4 av = *(const uint4*)(A + (size_t)(m0 + row) * K + k0 + c * 8);
            *(uint4*)((char*)&As[0][0] + row * 128 + csw * 16) = av;
            uint4 bv = *(const uint4*)(Bt + (size_t)(n0 + row) * K + k0 + c * 8);
            *(uint4*)((char*)&Bs[0][0] + row * 128 + csw * 16) = bv;
        }
        __syncthreads();
#pragma unroll
        for (int kf = 0; kf < 2; ++kf) {
            bf16x8 af[4], bfr[4];
#pragma unroll
            for (int mf = 0; mf < 4; ++mf) {
                int row = wm + mf * 16 + l15;
                int csw = (kf * 4 + lg) ^ (row & 7);
                af[mf] = *(const bf16x8*)((const char*)&As[0][0] + row * 128 + csw * 16);
            }
#pragma unroll
            for (int nf = 0; nf < 4; ++nf) {
                int row = wn + nf * 16 + l15;
                int csw = (kf * 4 + lg) ^ (row & 7);
                bfr[nf] = *(const bf16x8*)((const char*)&Bs[0][0] + row * 128 + csw * 16);
            }
#pragma unroll
            for (int mf = 0; mf < 4; ++mf)
#pragma unroll
                for (int nf = 0; nf < 4; ++nf)
                    acc[mf][nf] = __builtin_amdgcn_mfma_f32_16x16x32_bf16(
                        af[mf], bfr[nf], acc[mf][nf], 0, 0, 0);
        }
        __syncthreads();
    }
    // epilogue: C/D layout col = lane&15, row = (lane>>4)*4 + j
#pragma unroll
    for (int nf = 0; nf < 4; ++nf) {
        int col = n0 + wn + nf * 16 + l15;
        float bv = bias[col];
#pragma unroll
        for (int mf = 0; mf < 4; ++mf) {
#pragma unroll
            for (int j = 0; j < 4; ++j) {
                int row = m0 + wm + mf * 16 + lg * 4 + j;
                size_t idx = (size_t)row * N + col;
                float x = acc[mf][nf][j] + bv;
                if (MODE == 1) x = fmaxf(x, 0.f);
                Cb[idx] = __float2bfloat16(x);
            }
        }
    }
}

// ---------------- attention: MFMA, one block per (b,h) ----------------------
#define VP_ 168
__global__ __launch_bounds__(256, 2)
void attn_kernel(const bf16* __restrict__ qkv, const int* __restrict__ mask,
                 bf16* __restrict__ obf) {
    __shared__ alignas(16) unsigned short ldsbuf[32064];
    unsigned short* Kb = ldsbuf;                       // 10240 u16
    unsigned short* QP = ldsbuf + 10240;               // 10752 u16 (Q 10240 / Pb 10752)
    unsigned short* Vt = ldsbuf + 10240 + 10752;       // 10752 u16, [64][168]
    float* biasf = (float*)(ldsbuf + 10240 + 10752 + 10752);  // 160 f32

    const int bh = blockIdx.x;
    const int b = bh >> 3, h = bh & 7;
    const int tid = threadIdx.x, w = tid >> 6, lane = tid & 63;
    const int l15 = lane & 15, lg = lane >> 4;
    const size_t base = (size_t)b * S_ * 1536 + h * 64;
    const unsigned short* qk16 = (const unsigned short*)qkv;

    for (int i = tid; i < 160 * 8; i += 256) {
        int r = i >> 3, c = i & 7;
        int csw = c ^ (r & 7);
        uint4 kz = make_uint4(0u, 0u, 0u, 0u), qz = kz;
        if (r < 151) {
            kz = *(const uint4*)(qk16 + base + (size_t)r * 1536 + 512 + c * 8);
            qz = *(const uint4*)(qk16 + base + (size_t)r * 1536 + c * 8);
        }
        *(uint4*)((char*)Kb + r * 128 + csw * 16) = kz;
        *(uint4*)((char*)QP + r * 128 + csw * 16) = qz;
    }
    for (int i = tid; i < 160 * 8; i += 256) {
        int n = i >> 3, c = i & 7;
        u16x8 vv = {0, 0, 0, 0, 0, 0, 0, 0};
        if (n < 151) vv = *(const u16x8*)(qk16 + base + (size_t)n * 1536 + 1024 + c * 8);
#pragma unroll
        for (int e = 0; e < 8; ++e) Vt[(c * 8 + e) * VP_ + n] = vv[e];
    }
    if (tid < 160) {
        float bv;
        if (tid == 0) bv = 0.f;
        else if (tid <= 150) bv = (mask[b * T_ + tid - 1] != 0) ? 0.f : -1e9f;
        else bv = -1e9f;
        biasf[tid] = bv;
    }
    __syncthreads();

    int r0 = w * 16 + l15;
    int r1 = r0 + 64;
    int r2 = r0 + 128; if (r2 > 159) r2 = 159;
    bf16x8 q00 = *(const bf16x8*)((const char*)QP + r0 * 128 + ((lg)     ^ (r0 & 7)) * 16);
    bf16x8 q01 = *(const bf16x8*)((const char*)QP + r0 * 128 + ((4 + lg) ^ (r0 & 7)) * 16);
    bf16x8 q10 = *(const bf16x8*)((const char*)QP + r1 * 128 + ((lg)     ^ (r1 & 7)) * 16);
    bf16x8 q11 = *(const bf16x8*)((const char*)QP + r1 * 128 + ((4 + lg) ^ (r1 & 7)) * 16);
    bf16x8 q20 = *(const bf16x8*)((const char*)QP + r2 * 128 + ((lg)     ^ (r2 & 7)) * 16);
    bf16x8 q21 = *(const bf16x8*)((const char*)QP + r2 * 128 + ((4 + lg) ^ (r2 & 7)) * 16);
    float bc0 = biasf[l15],       bc1 = biasf[16 + l15],  bc2 = biasf[32 + l15];
    float bc3 = biasf[48 + l15],  bc4 = biasf[64 + l15],  bc5 = biasf[80 + l15];
    float bc6 = biasf[96 + l15],  bc7 = biasf[112 + l15], bc8 = biasf[128 + l15];
    float bc9 = biasf[144 + l15];
    __syncthreads();   // QP now becomes the per-wave P buffer

    bf16* Pw = (bf16*)(QP + w * 16 * VP_);
    const float scale = 0.125f;

#pragma unroll
    for (int mi = 0; mi < 3; ++mi) {
        int mt = w + mi * 4;
        if (mt < 10) {
            bf16x8 qk0 = (mi == 0) ? q00 : (mi == 1) ? q10 : q20;
            bf16x8 qk1 = (mi == 0) ? q01 : (mi == 1) ? q11 : q21;
            f32x4 sc[10] = {};
#pragma unroll
            for (int nt = 0; nt < 10; ++nt) {
                int kr = nt * 16 + l15;
                bf16x8 kb0 = *(const bf16x8*)((const char*)Kb + kr * 128 + ((lg)     ^ (kr & 7)) * 16);
                bf16x8 kb1 = *(const bf16x8*)((const char*)Kb + kr * 128 + ((4 + lg) ^ (kr & 7)) * 16);
                sc[nt] = __builtin_amdgcn_mfma_f32_16x16x32_bf16(qk0, kb0, sc[nt], 0, 0, 0);
                sc[nt] = __builtin_amdgcn_mfma_f32_16x16x32_bf16(qk1, kb1, sc[nt], 0, 0, 0);
            }
            float m0r = -3e38f, m1r = -3e38f, m2r = -3e38f, m3r = -3e38f;
#pragma unroll
            for (int nt = 0; nt < 10; ++nt) {
                float bv = (nt == 0) ? bc0 : (nt == 1) ? bc1 : (nt == 2) ? bc2 :
                           (nt == 3) ? bc3 : (nt == 4) ? bc4 : (nt == 5) ? bc5 :
                           (nt == 6) ? bc6 : (nt == 7) ? bc7 : (nt == 8) ? bc8 : bc9;
                sc[nt][0] = sc[nt][0] * scale + bv;  m0r = fmaxf(m0r, sc[nt][0]);
                sc[nt][1] = sc[nt][1] * scale + bv;  m1r = fmaxf(m1r, sc[nt][1]);
                sc[nt][2] = sc[nt][2] * scale + bv;  m2r = fmaxf(m2r, sc[nt][2]);
                sc[nt][3] = sc[nt][3] * scale + bv;  m3r = fmaxf(m3r, sc[nt][3]);
            }
#pragma unroll
            for (int off = 1; off < 16; off <<= 1) {
                m0r = fmaxf(m0r, __shfl_xor(m0r, off));
                m1r = fmaxf(m1r, __shfl_xor(m1r, off));
                m2r = fmaxf(m2r, __shfl_xor(m2r, off));
                m3r = fmaxf(m3r, __shfl_xor(m3r, off));
            }
            float s0 = 0.f, s1 = 0.f, s2 = 0.f, s3 = 0.f;
#pragma unroll
            for (int nt = 0; nt < 10; ++nt) {
                sc[nt][0] = __expf(sc[nt][0] - m0r);  s0 += sc[nt][0];
                sc[nt][1] = __expf(sc[nt][1] - m1r);  s1 += sc[nt][1];
                sc[nt][2] = __expf(sc[nt][2] - m2r);  s2 += sc[nt][2];
                sc[nt][3] = __expf(sc[nt][3] - m3r);  s3 += sc[nt][3];
            }
#pragma unroll
            for (int off = 1; off < 16; off <<= 1) {
                s0 += __shfl_xor(s0, off);
                s1 += __shfl_xor(s1, off);
                s2 += __shfl_xor(s2, off);
                s3 += __shfl_xor(s3, off);
            }
            s0 = 1.f / s0; s1 = 1.f / s1; s2 = 1.f / s2; s3 = 1.f / s3;
#pragma unroll
            for (int nt = 0; nt < 10; ++nt) {
                int cb = nt * 16 + l15;
                Pw[(lg * 4 + 0) * VP_ + cb] = __float2bfloat16(sc[nt][0]);
                Pw[(lg * 4 + 1) * VP_ + cb] = __float2bfloat16(sc[nt][1]);
                Pw[(lg * 4 + 2) * VP_ + cb] = __float2bfloat16(sc[nt][2]);
                Pw[(lg * 4 + 3) * VP_ + cb] = __float2bfloat16(sc[nt][3]);
            }
            f32x4 oc[4] = {};
#pragma unroll
            for (int nc = 0; nc < 5; ++nc) {
                bf16x8 pa = *(const bf16x8*)((const unsigned short*)Pw + l15 * VP_ + nc * 32 + lg * 8);
#pragma unroll
                for (int dt = 0; dt < 4; ++dt) {
                    bf16x8 vb = *(const bf16x8*)(Vt + (dt * 16 + l15) * VP_ + nc * 32 + lg * 8);
                    oc[dt] = __builtin_amdgcn_mfma_f32_16x16x32_bf16(pa, vb, oc[dt], 0, 0, 0);
                }
            }
            int orow = mt * 16 + lg * 4;
#pragma unroll
            for (int dt = 0; dt < 4; ++dt) {
                int d = h * 64 + dt * 16 + l15;
                if (orow + 0 < 151) obf[((size_t)(b * S_ + orow + 0)) * E_ + d] = __float2bfloat16(oc[dt][0] * s0);
                if (orow + 1 < 151) obf[((size_t)(b * S_ + orow + 1)) * E_ + d] = __float2bfloat16(oc[dt][1] * s1);
                if (orow + 2 < 151) obf[((size_t)(b * S_ + orow + 2)) * E_ + d] = __float2bfloat16(oc[dt][2] * s2);
                if (orow + 3 < 151) obf[((size_t)(b * S_ + orow + 3)) * E_ + d] = __float2bfloat16(oc[dt][3] * s3);
            }
        }
    }
}

// ---------------- fused residual + LayerNorm (4 rows/block, 1 wave/row) ------
// t = x32 + bf2f(add_bf);  y = LN(t)*g + b;  x32 = y; xbf = bf16(y)
__global__ __launch_bounds__(256)
void ln_res_kernel(const bf16* __restrict__ add_bf, const float* __restrict__ gw,
                   const float* __restrict__ bw, float* __restrict__ x32,
                   bf16* __restrict__ xbf) {
    int lane = threadIdx.x & 63;
    int row = blockIdx.x * 4 + (threadIdx.x >> 6);
    size_t o = (size_t)row * E_ + lane * 8;
    f32x4 a0 = *(const f32x4*)(x32 + o);
    f32x4 a1 = *(const f32x4*)(x32 + o + 4);
    u16x8 hb = *(const u16x8*)((const unsigned short*)add_bf + o);
    f32x4 t0, t1;
    t0[0] = a0[0] + b2f(hb[0]); t0[1] = a0[1] + b2f(hb[1]);
    t0[2] = a0[2] + b2f(hb[2]); t0[3] = a0[3] + b2f(hb[3]);
    t1[0] = a1[0] + b2f(hb[4]); t1[1] = a1[1] + b2f(hb[5]);
    t1[2] = a1[2] + b2f(hb[6]); t1[3] = a1[3] + b2f(hb[7]);
    float s = t0[0] + t0[1] + t0[2] + t0[3] + t1[0] + t1[1] + t1[2] + t1[3];
#pragma unroll
    for (int off = 1; off < 64; off <<= 1) s += __shfl_xor(s, off);
    float mean = s * (1.0f / 512.0f);
    f32x4 d0 = t0 - mean, d1 = t1 - mean;
    float q = d0[0]*d0[0] + d0[1]*d0[1] + d0[2]*d0[2] + d0[3]*d0[3]
            + d1[0]*d1[0] + d1[1]*d1[1] + d1[2]*d1[2] + d1[3]*d1[3];
#pragma unroll
    for (int off = 1; off < 64; off <<= 1) q += __shfl_xor(q, off);
    float rstd = rsqrtf(q * (1.0f / 512.0f) + 1e-5f);
    f32x4 g0 = *(const f32x4*)(gw + lane * 8);
    f32x4 g1 = *(const f32x4*)(gw + lane * 8 + 4);
    f32x4 bb0 = *(const f32x4*)(bw + lane * 8);
    f32x4 bb1 = *(const f32x4*)(bw + lane * 8 + 4);
    f32x4 y0 = d0 * rstd * g0 + bb0;
    f32x4 y1 = d1 * rstd * g1 + bb1;
    *(f32x4*)(x32 + o) = y0;
    *(f32x4*)(x32 + o + 4) = y1;
    union { unsigned short s[8]; uint4 v; } pk;
    pk.s[0] = f2b(y0[0]); pk.s[1] = f2b(y0[1]); pk.s[2] = f2b(y0[2]); pk.s[3] = f2b(y0[3]);
    pk.s[4] = f2b(y1[0]); pk.s[5] = f2b(y1[1]); pk.s[6] = f2b(y1[2]); pk.s[7] = f2b(y1[3]);
    *(uint4*)((unsigned short*)xbf + o) = pk.v;
}

// ---------------- final: out[b,:] = x32[b*S + 0, :] --------------------------
__global__ __launch_bounds__(256)
void out_kernel(const float* __restrict__ x32, float* __restrict__ out) {
    int i = blockIdx.x * 256 + threadIdx.x;
    int b = i >> 9, e = i & 511;
    out[i] = x32[(size_t)b * S_ * E_ + e];
}

extern "C" void kernel_launch(void* const* d_in, const int* in_sizes, int n_in,
                              void* d_out, int out_size, void* d_ws, size_t ws_size,
                              hipStream_t stream) {
    (void)in_sizes; (void)n_in; (void)out_size; (void)ws_size;
    const int*   token_type = (const int*)d_in[0];
    const int*   mask       = (const int*)d_in[1];
    const int*   dec_idx    = (const int*)d_in[2];
    const float* action_val = (const float*)d_in[3];
    const float* dis_val    = (const float*)d_in[4];
    const float* v_val      = (const float*)d_in[5];
    const float* action_W   = (const float*)d_in[6];
    const float* action_b   = (const float*)d_in[7];
    const float* dis_W      = (const float*)d_in[8];
    const float* dis_b      = (const float*)d_in[9];
    const float* v_W        = (const float*)d_in[10];
    const float* v_b        = (const float*)d_in[11];
    const float* dec_emb    = (const float*)d_in[12];
    const float* pos        = (const float*)d_in[13];
    const float* cls        = (const float*)d_in[14];
    const float* qkv_W      = (const float*)d_in[15];
    const float* qkv_b      = (const float*)d_in[16];
    const float* out_W      = (const float*)d_in[17];
    const float* out_b      = (const float*)d_in[18];
    const float* ln1_g      = (const float*)d_in[19];
    const float* ln1_b      = (const float*)d_in[20];
    const float* ff1_W      = (const float*)d_in[21];
    const float* ff1_b      = (const float*)d_in[22];
    const float* ff2_W      = (const float*)d_in[23];
    const float* ff2_b      = (const float*)d_in[24];
    const float* ln2_g      = (const float*)d_in[25];
    const float* ln2_b      = (const float*)d_in[26];

    char* ws = (char*)d_ws;
    size_t off = 0;
    auto alloc = [&](size_t bytes) {
        char* p = ws + off;
        off += (bytes + 255) & ~(size_t)255;
        return p;
    };
    bf16* qkvT = (bf16*)alloc((size_t)L_ * 1536 * 512 * 2);  //  9.4 MB
    bf16* outT = (bf16*)alloc((size_t)L_ * 512 * 512 * 2);   //  3.1 MB
    bf16* ff1T = (bf16*)alloc((size_t)L_ * 2048 * 512 * 2);  // 12.6 MB
    bf16* ff2T = (bf16*)alloc((size_t)L_ * 512 * 2048 * 2);  // 12.6 MB
    float* x32 = (float*)alloc((size_t)M_ * E_ * 4);         // 79.2 MB residual (f32)
    bf16*  xbf = (bf16*)alloc((size_t)M_ * E_ * 2);          // 39.6 MB x(bf16) / attn-out
    char*  arena = alloc((size_t)M_ * E_ * 4);               // 79.2 MB shared scratch

    dim3 blk(256);
    transpose_cast_kernel<<<dim3(8, 24, L_), blk, 0, stream>>>(qkv_W, qkvT, 512, 1536);
    transpose_cast_kernel<<<dim3(8, 8,  L_), blk, 0, stream>>>(out_W, outT, 512, 512);
    transpose_cast_kernel<<<dim3(8, 32, L_), blk, 0, stream>>>(ff1_W, ff1T, 512, 2048);
    transpose_cast_kernel<<<dim3(32, 8, L_), blk, 0, stream>>>(ff2_W, ff2T, 2048, 512);

    embed_kernel<<<dim3(M_ / 4), blk, 0, stream>>>(token_type, dec_idx, action_val, dis_val, v_val,
        action_W, action_b, dis_W, dis_b, v_W, v_b, dec_emb, pos, cls, x32, xbf);

    const int HALF_ROWS = 19328;                 // 128 batches * 151
    const size_t HOFF = (size_t)9728 * FF_ * 2;  // hbf_c bytes (76 tiles)
    const int ffTiles[4] = {76, 76, 76, 74};
    const int ffBase[4]  = {0, 9728, 19456, 29184};

    for (int l = 0; l < L_; ++l) {
        const bf16* qT = qkvT + (size_t)l * 1536 * 512;
        const bf16* oT = outT + (size_t)l * 512 * 512;
        const bf16* f1 = ff1T + (size_t)l * 2048 * 512;
        const bf16* f2 = ff2T + (size_t)l * 512 * 2048;

        // QKV + attention, chunked over 2 batch-halves (arena = qkv chunk)
        for (int c = 0; c < 2; ++c) {
            gemm_kernel<3><<<dim3(151 * 12), blk, 0, stream>>>(
                xbf + (size_t)c * HALF_ROWS * E_, qT, qkv_b + l * 1536,
                (bf16*)arena, 1536, 512);
            attn_kernel<<<dim3(128 * H_), blk, 0, stream>>>(
                (const bf16*)arena, mask + c * 128 * T_,
                xbf + (size_t)c * HALF_ROWS * E_);   // attn-out overwrites xbf
        }
        // proj (bf16 out, no residual) -> arena, then fused res+LN1
        gemm_kernel<3><<<dim3(302 * 4), blk, 0, stream>>>(
            xbf, oT, out_b + l * 512, (bf16*)arena, 512, 512);
        ln_res_kernel<<<dim3(M_ / 4), blk, 0, stream>>>(
            (const bf16*)arena, ln1_g + l * 512, ln1_b + l * 512, x32, xbf);
        // FF, chunked over 4 row-groups (arena = hbf_c | ff2out_c)
        for (int c = 0; c < 4; ++c) {
            int rb = ffBase[c], nt = ffTiles[c];
            gemm_kernel<1><<<dim3(nt * 16), blk, 0, stream>>>(
                xbf + (size_t)rb * E_, f1, ff1_b + l * 2048,
                (bf16*)arena, 2048, 512);
            gemm_kernel<3><<<dim3(nt * 4), blk, 0, stream>>>(
                (const bf16*)arena, f2, ff2_b + l * 512,
                (bf16*)(arena + HOFF), 512, 2048);
            ln_res_kernel<<<dim3(nt * 128 / 4), blk, 0, stream>>>(
                (const bf16*)(arena + HOFF), ln2_g + l * 512, ln2_b + l * 512,
                x32 + (size_t)rb * E_, xbf + (size_t)rb * E_);
        }
    }
    out_kernel<<<dim3(B_ * E_ / 256), blk, 0, stream>>>(x32, (float*)d_out);
}

// Round 5
// 2706.879 us; speedup vs baseline: 15.1385x; 1.2712x over previous
//
#include <hip/hip_runtime.h>
#include <hip/hip_bf16.h>
#include <stdint.h>

#define B_ 256
#define T_ 150
#define S_ 151
#define E_ 512
#define H_ 8
#define L_ 6
#define FF_ 2048
#define M_ (B_*S_)   // 38656 = 302*128

typedef __hip_bfloat16 bf16;
typedef __bf16 bf16x8 __attribute__((ext_vector_type(8)));
typedef float f32x4 __attribute__((ext_vector_type(4)));
typedef unsigned short u16x8 __attribute__((ext_vector_type(8)));

__device__ inline unsigned short f2b(float x) {
    union { __hip_bfloat16 h; unsigned short u; } c;
    c.h = __float2bfloat16(x);
    return c.u;
}
__device__ inline float b2f(unsigned short u) {
    union { uint32_t u; float f; } c;
    c.u = (uint32_t)u << 16;
    return c.f;
}

// async global->LDS 16B; LDS dest must be wave-uniform base + lane*16 (linear)
__device__ __forceinline__ void gl16(const void* g, void* l) {
    __builtin_amdgcn_global_load_lds(
        (const __attribute__((address_space(1))) unsigned int*)g,
        (__attribute__((address_space(3))) unsigned int*)l, 16, 0, 0);
}

// ---------------- weight transpose f32[K][N] -> bf16[N][K], batched over L ----
__global__ __launch_bounds__(256)
void transpose_cast_kernel(const float* __restrict__ src, bf16* __restrict__ dst,
                           int K, int N) {
    __shared__ float tile[64][65];
    int l = blockIdx.z;
    const float* s = src + (size_t)l * K * N;
    bf16* d = dst + (size_t)l * K * N;
    int bk = blockIdx.x * 64, bn = blockIdx.y * 64;
    int col = threadIdx.x & 63, rg = threadIdx.x >> 6;
#pragma unroll
    for (int i = 0; i < 16; ++i) {
        int r = i * 4 + rg;
        tile[r][col] = s[(size_t)(bk + r) * N + bn + col];
    }
    __syncthreads();
#pragma unroll
    for (int i = 0; i < 16; ++i) {
        int r = i * 4 + rg;
        d[(size_t)(bn + r) * K + bk + col] = __float2bfloat16(tile[col][r]);
    }
}

// ---------------- token embedding + pos + cls -> x32, xbf (4 rows/block) -----
__global__ __launch_bounds__(256)
void embed_kernel(const int* __restrict__ tt, const int* __restrict__ dec_idx,
                  const float* __restrict__ action_val, const float* __restrict__ dis_val,
                  const float* __restrict__ v_val,
                  const float* __restrict__ action_W, const float* __restrict__ action_b,
                  const float* __restrict__ dis_W, const float* __restrict__ dis_b,
                  const float* __restrict__ v_W, const float* __restrict__ v_b,
                  const float* __restrict__ dec_emb, const float* __restrict__ pos,
                  const float* __restrict__ cls,
                  float* __restrict__ x32, bf16* __restrict__ xbf) {
    int lane = threadIdx.x & 63;
    int bs = blockIdx.x * 4 + (threadIdx.x >> 6);
    int b = bs / S_, s = bs - b * S_;
    int e0 = lane * 8;
    f32x4 v0, v1;
    if (s == 0) {
        v0 = *(const f32x4*)(cls + e0);
        v1 = *(const f32x4*)(cls + e0 + 4);
    } else {
        int t = s - 1;
        int ty = tt[b * T_ + t];
        if (ty == 0) {
            float av = action_val[b * T_ + t];
            f32x4 w0 = *(const f32x4*)(action_W + e0);
            f32x4 w1 = *(const f32x4*)(action_W + e0 + 4);
            f32x4 b0 = *(const f32x4*)(action_b + e0);
            f32x4 b1 = *(const f32x4*)(action_b + e0 + 4);
            v0 = w0 * av + b0;  v1 = w1 * av + b1;
        } else if (ty == 1) {
            v0 = *(const f32x4*)(dis_b + e0) + *(const f32x4*)(v_b + e0);
            v1 = *(const f32x4*)(dis_b + e0 + 4) + *(const f32x4*)(v_b + e0 + 4);
#pragma unroll
            for (int i = 0; i < 10; ++i) {
                float dv = dis_val[(b * T_ + t) * 10 + i];
                v0 += *(const f32x4*)(dis_W + i * E_ + e0) * dv;
                v1 += *(const f32x4*)(dis_W + i * E_ + e0 + 4) * dv;
            }
#pragma unroll
            for (int i = 0; i < 3; ++i) {
                float vv = v_val[(b * T_ + t) * 3 + i];
                v0 += *(const f32x4*)(v_W + i * E_ + e0) * vv;
                v1 += *(const f32x4*)(v_W + i * E_ + e0 + 4) * vv;
            }
        } else {
            const float* de = dec_emb + (size_t)dec_idx[b * T_ + t] * E_;
            v0 = *(const f32x4*)(de + e0);
            v1 = *(const f32x4*)(de + e0 + 4);
        }
        v0 += *(const f32x4*)(pos + (size_t)t * E_ + e0);
        v1 += *(const f32x4*)(pos + (size_t)t * E_ + e0 + 4);
    }
    size_t o = (size_t)bs * E_ + e0;
    *(f32x4*)(x32 + o) = v0;
    *(f32x4*)(x32 + o + 4) = v1;
    union { unsigned short s[8]; uint4 v; } pk;
    pk.s[0] = f2b(v0[0]); pk.s[1] = f2b(v0[1]); pk.s[2] = f2b(v0[2]); pk.s[3] = f2b(v0[3]);
    pk.s[4] = f2b(v1[0]); pk.s[5] = f2b(v1[1]); pk.s[6] = f2b(v1[2]); pk.s[7] = f2b(v1[3]);
    *(uint4*)((unsigned short*)xbf + o) = pk.v;
}

// ---------------- bf16 MFMA GEMM: C = A[rows,K] * Bt[N,K] (+bias[,relu]) -----
// 128x128 tile, BK=64, 4 waves (2x2), 4x4 frags of 16x16x32.
// Staging via global_load_lds width=16: LINEAR LDS dest + inverse-swizzled
// global source; read side applies the same XOR swizzle (rule #21 pattern).
// XCD-chunked n-fastest tile mapping (bijective m204 form).
// MODE: 1 = relu(acc+bias) -> bf16 | 3 = acc+bias -> bf16
template<int MODE>
__global__ __launch_bounds__(256, 2)
void gemm_kernel(const bf16* __restrict__ A, const bf16* __restrict__ Bt,
                 const float* __restrict__ bias, bf16* __restrict__ Cb,
                 int N, int K) {
    __shared__ alignas(16) bf16 As[128][64];
    __shared__ alignas(16) bf16 Bs[128][64];
    const int tid = threadIdx.x;
    const int wave = tid >> 6, lane = tid & 63;
    const int nwg = gridDim.x, bid = blockIdx.x;
    const int Nt = N >> 7;
    const int q = nwg >> 3, r = nwg & 7;
    const int xcd = bid & 7, slot = bid >> 3;
    const int wgid = (xcd < r ? xcd * (q + 1) : r * (q + 1) + (xcd - r) * q) + slot;
    const int mt = wgid / Nt, ntl = wgid - mt * Nt;
    const int m0 = mt * 128, n0 = ntl * 128;
    const int wm = (wave >> 1) * 64, wn = (wave & 1) * 64;
    const int l15 = lane & 15, lg = lane >> 4;

    f32x4 acc[4][4] = {};

    for (int k0 = 0; k0 < K; k0 += 64) {
        // async stage: 1024 16B chunks, linear LDS dest = chunk*16,
        // global column pre-swizzled so read-side XOR recovers identity
#pragma unroll
        for (int i = 0; i < 4; ++i) {
            int chunk = i * 256 + tid;      // 0..1023
            int row = chunk >> 3, cl = chunk & 7;
            int gc = cl ^ (row & 7);
            gl16(A + (size_t)(m0 + row) * K + k0 + gc * 8,
                 (char*)&As[0][0] + chunk * 16);
            gl16(Bt + (size_t)(n0 + row) * K + k0 + gc * 8,
                 (char*)&Bs[0][0] + chunk * 16);
        }
        __syncthreads();
#pragma unroll
        for (int kf = 0; kf < 2; ++kf) {
            bf16x8 af[4], bfr[4];
#pragma unroll
            for (int mf = 0; mf < 4; ++mf) {
                int row = wm + mf * 16 + l15;
                int csw = (kf * 4 + lg) ^ (row & 7);
                af[mf] = *(const bf16x8*)((const char*)&As[0][0] + row * 128 + csw * 16);
            }
#pragma unroll
            for (int nf = 0; nf < 4; ++nf) {
                int row = wn + nf * 16 + l15;
                int csw = (kf * 4 + lg) ^ (row & 7);
                bfr[nf] = *(const bf16x8*)((const char*)&Bs[0][0] + row * 128 + csw * 16);
            }
#pragma unroll
            for (int mf = 0; mf < 4; ++mf)
#pragma unroll
                for (int nf = 0; nf < 4; ++nf)
                    acc[mf][nf] = __builtin_amdgcn_mfma_f32_16x16x32_bf16(
                        af[mf], bfr[nf], acc[mf][nf], 0, 0, 0);
        }
        __syncthreads();
    }
    // epilogue: C/D layout col = lane&15, row = (lane>>4)*4 + j
#pragma unroll
    for (int nf = 0; nf < 4; ++nf) {
        int col = n0 + wn + nf * 16 + l15;
        float bv = bias[col];
#pragma unroll
        for (int mf = 0; mf < 4; ++mf) {
#pragma unroll
            for (int j = 0; j < 4; ++j) {
                int row = m0 + wm + mf * 16 + lg * 4 + j;
                size_t idx = (size_t)row * N + col;
                float x = acc[mf][nf][j] + bv;
                if (MODE == 1) x = fmaxf(x, 0.f);
                Cb[idx] = __float2bfloat16(x);
            }
        }
    }
}

// ---------------- attention: MFMA, one block per (b,h) ----------------------
#define VP_ 168
__global__ __launch_bounds__(256, 2)
void attn_kernel(const bf16* __restrict__ qkv, const int* __restrict__ mask,
                 bf16* __restrict__ obf) {
    __shared__ alignas(16) unsigned short ldsbuf[32064];
    unsigned short* Kb = ldsbuf;                       // 10240 u16
    unsigned short* QP = ldsbuf + 10240;               // 10752 u16 (Q 10240 / Pb 10752)
    unsigned short* Vt = ldsbuf + 10240 + 10752;       // 10752 u16, [64][168]
    float* biasf = (float*)(ldsbuf + 10240 + 10752 + 10752);  // 160 f32

    const int bh = blockIdx.x;
    const int b = bh >> 3, h = bh & 7;
    const int tid = threadIdx.x, w = tid >> 6, lane = tid & 63;
    const int l15 = lane & 15, lg = lane >> 4;
    const size_t base = (size_t)b * S_ * 1536 + h * 64;
    const unsigned short* qk16 = (const unsigned short*)qkv;

    for (int i = tid; i < 160 * 8; i += 256) {
        int r = i >> 3, c = i & 7;
        int csw = c ^ (r & 7);
        uint4 kz = make_uint4(0u, 0u, 0u, 0u), qz = kz;
        if (r < 151) {
            kz = *(const uint4*)(qk16 + base + (size_t)r * 1536 + 512 + c * 8);
            qz = *(const uint4*)(qk16 + base + (size_t)r * 1536 + c * 8);
        }
        *(uint4*)((char*)Kb + r * 128 + csw * 16) = kz;
        *(uint4*)((char*)QP + r * 128 + csw * 16) = qz;
    }
    for (int i = tid; i < 160 * 8; i += 256) {
        int n = i >> 3, c = i & 7;
        u16x8 vv = {0, 0, 0, 0, 0, 0, 0, 0};
        if (n < 151) vv = *(const u16x8*)(qk16 + base + (size_t)n * 1536 + 1024 + c * 8);
#pragma unroll
        for (int e = 0; e < 8; ++e) Vt[(c * 8 + e) * VP_ + n] = vv[e];
    }
    if (tid < 160) {
        float bv;
        if (tid == 0) bv = 0.f;
        else if (tid <= 150) bv = (mask[b * T_ + tid - 1] != 0) ? 0.f : -1e9f;
        else bv = -1e9f;
        biasf[tid] = bv;
    }
    __syncthreads();

    int r0 = w * 16 + l15;
    int r1 = r0 + 64;
    int r2 = r0 + 128; if (r2 > 159) r2 = 159;
    bf16x8 q00 = *(const bf16x8*)((const char*)QP + r0 * 128 + ((lg)     ^ (r0 & 7)) * 16);
    bf16x8 q01 = *(const bf16x8*)((const char*)QP + r0 * 128 + ((4 + lg) ^ (r0 & 7)) * 16);
    bf16x8 q10 = *(const bf16x8*)((const char*)QP + r1 * 128 + ((lg)     ^ (r1 & 7)) * 16);
    bf16x8 q11 = *(const bf16x8*)((const char*)QP + r1 * 128 + ((4 + lg) ^ (r1 & 7)) * 16);
    bf16x8 q20 = *(const bf16x8*)((const char*)QP + r2 * 128 + ((lg)     ^ (r2 & 7)) * 16);
    bf16x8 q21 = *(const bf16x8*)((const char*)QP + r2 * 128 + ((4 + lg) ^ (r2 & 7)) * 16);
    float bc0 = biasf[l15],       bc1 = biasf[16 + l15],  bc2 = biasf[32 + l15];
    float bc3 = biasf[48 + l15],  bc4 = biasf[64 + l15],  bc5 = biasf[80 + l15];
    float bc6 = biasf[96 + l15],  bc7 = biasf[112 + l15], bc8 = biasf[128 + l15];
    float bc9 = biasf[144 + l15];
    __syncthreads();   // QP now becomes the per-wave P buffer

    bf16* Pw = (bf16*)(QP + w * 16 * VP_);
    const float scale = 0.125f;

#pragma unroll
    for (int mi = 0; mi < 3; ++mi) {
        int mt = w + mi * 4;
        if (mt < 10) {
            bf16x8 qk0 = (mi == 0) ? q00 : (mi == 1) ? q10 : q20;
            bf16x8 qk1 = (mi == 0) ? q01 : (mi == 1) ? q11 : q21;
            f32x4 sc[10] = {};
#pragma unroll
            for (int nt = 0; nt < 10; ++nt) {
                int kr = nt * 16 + l15;
                bf16x8 kb0 = *(const bf16x8*)((const char*)Kb + kr * 128 + ((lg)     ^ (kr & 7)) * 16);
                bf16x8 kb1 = *(const bf16x8*)((const char*)Kb + kr * 128 + ((4 + lg) ^ (kr & 7)) * 16);
                sc[nt] = __builtin_amdgcn_mfma_f32_16x16x32_bf16(qk0, kb0, sc[nt], 0, 0, 0);
                sc[nt] = __builtin_amdgcn_mfma_f32_16x16x32_bf16(qk1, kb1, sc[nt], 0, 0, 0);
            }
            float m0r = -3e38f, m1r = -3e38f, m2r = -3e38f, m3r = -3e38f;
#pragma unroll
            for (int nt = 0; nt < 10; ++nt) {
                float bv = (nt == 0) ? bc0 : (nt == 1) ? bc1 : (nt == 2) ? bc2 :
                           (nt == 3) ? bc3 : (nt == 4) ? bc4 : (nt == 5) ? bc5 :
                           (nt == 6) ? bc6 : (nt == 7) ? bc7 : (nt == 8) ? bc8 : bc9;
                sc[nt][0] = sc[nt][0] * scale + bv;  m0r = fmaxf(m0r, sc[nt][0]);
                sc[nt][1] = sc[nt][1] * scale + bv;  m1r = fmaxf(m1r, sc[nt][1]);
                sc[nt][2] = sc[nt][2] * scale + bv;  m2r = fmaxf(m2r, sc[nt][2]);
                sc[nt][3] = sc[nt][3] * scale + bv;  m3r = fmaxf(m3r, sc[nt][3]);
            }
#pragma unroll
            for (int off = 1; off < 16; off <<= 1) {
                m0r = fmaxf(m0r, __shfl_xor(m0r, off));
                m1r = fmaxf(m1r, __shfl_xor(m1r, off));
                m2r = fmaxf(m2r, __shfl_xor(m2r, off));
                m3r = fmaxf(m3r, __shfl_xor(m3r, off));
            }
            float s0 = 0.f, s1 = 0.f, s2 = 0.f, s3 = 0.f;
#pragma unroll
            for (int nt = 0; nt < 10; ++nt) {
                sc[nt][0] = __expf(sc[nt][0] - m0r);  s0 += sc[nt][0];
                sc[nt][1] = __expf(sc[nt][1] - m1r);  s1 += sc[nt][1];
                sc[nt][2] = __expf(sc[nt][2] - m2r);  s2 += sc[nt][2];
                sc[nt][3] = __expf(sc[nt][3] - m3r);  s3 += sc[nt][3];
            }
#pragma unroll
            for (int off = 1; off < 16; off <<= 1) {
                s0 += __shfl_xor(s0, off);
                s1 += __shfl_xor(s1, off);
                s2 += __shfl_xor(s2, off);
                s3 += __shfl_xor(s3, off);
            }
            s0 = 1.f / s0; s1 = 1.f / s1; s2 = 1.f / s2; s3 = 1.f / s3;
#pragma unroll
            for (int nt = 0; nt < 10; ++nt) {
                int cb = nt * 16 + l15;
                Pw[(lg * 4 + 0) * VP_ + cb] = __float2bfloat16(sc[nt][0]);
                Pw[(lg * 4 + 1) * VP_ + cb] = __float2bfloat16(sc[nt][1]);
                Pw[(lg * 4 + 2) * VP_ + cb] = __float2bfloat16(sc[nt][2]);
                Pw[(lg * 4 + 3) * VP_ + cb] = __float2bfloat16(sc[nt][3]);
            }
            f32x4 oc[4] = {};
#pragma unroll
            for (int nc = 0; nc < 5; ++nc) {
                bf16x8 pa = *(const bf16x8*)((const unsigned short*)Pw + l15 * VP_ + nc * 32 + lg * 8);
#pragma unroll
                for (int dt = 0; dt < 4; ++dt) {
                    bf16x8 vb = *(const bf16x8*)(Vt + (dt * 16 + l15) * VP_ + nc * 32 + lg * 8);
                    oc[dt] = __builtin_amdgcn_mfma_f32_16x16x32_bf16(pa, vb, oc[dt], 0, 0, 0);
                }
            }
            int orow = mt * 16 + lg * 4;
#pragma unroll
            for (int dt = 0; dt < 4; ++dt) {
                int d = h * 64 + dt * 16 + l15;
                if (orow + 0 < 151) obf[((size_t)(b * S_ + orow + 0)) * E_ + d] = __float2bfloat16(oc[dt][0] * s0);
                if (orow + 1 < 151) obf[((size_t)(b * S_ + orow + 1)) * E_ + d] = __float2bfloat16(oc[dt][1] * s1);
                if (orow + 2 < 151) obf[((size_t)(b * S_ + orow + 2)) * E_ + d] = __float2bfloat16(oc[dt][2] * s2);
                if (orow + 3 < 151) obf[((size_t)(b * S_ + orow + 3)) * E_ + d] = __float2bfloat16(oc[dt][3] * s3);
            }
        }
    }
}

// ---------------- fused residual + LayerNorm (4 rows/block, 1 wave/row) ------
// t = x32 + bf2f(add_bf);  y = LN(t)*g + b;  x32 = y; xbf = bf16(y)
__global__ __launch_bounds__(256)
void ln_res_kernel(const bf16* __restrict__ add_bf, const float* __restrict__ gw,
                   const float* __restrict__ bw, float* __restrict__ x32,
                   bf16* __restrict__ xbf) {
    int lane = threadIdx.x & 63;
    int row = blockIdx.x * 4 + (threadIdx.x >> 6);
    size_t o = (size_t)row * E_ + lane * 8;
    f32x4 a0 = *(const f32x4*)(x32 + o);
    f32x4 a1 = *(const f32x4*)(x32 + o + 4);
    u16x8 hb = *(const u16x8*)((const unsigned short*)add_bf + o);
    f32x4 t0, t1;
    t0[0] = a0[0] + b2f(hb[0]); t0[1] = a0[1] + b2f(hb[1]);
    t0[2] = a0[2] + b2f(hb[2]); t0[3] = a0[3] + b2f(hb[3]);
    t1[0] = a1[0] + b2f(hb[4]); t1[1] = a1[1] + b2f(hb[5]);
    t1[2] = a1[2] + b2f(hb[6]); t1[3] = a1[3] + b2f(hb[7]);
    float s = t0[0] + t0[1] + t0[2] + t0[3] + t1[0] + t1[1] + t1[2] + t1[3];
#pragma unroll
    for (int off = 1; off < 64; off <<= 1) s += __shfl_xor(s, off);
    float mean = s * (1.0f / 512.0f);
    f32x4 d0 = t0 - mean, d1 = t1 - mean;
    float q = d0[0]*d0[0] + d0[1]*d0[1] + d0[2]*d0[2] + d0[3]*d0[3]
            + d1[0]*d1[0] + d1[1]*d1[1] + d1[2]*d1[2] + d1[3]*d1[3];
#pragma unroll
    for (int off = 1; off < 64; off <<= 1) q += __shfl_xor(q, off);
    float rstd = rsqrtf(q * (1.0f / 512.0f) + 1e-5f);
    f32x4 g0 = *(const f32x4*)(gw + lane * 8);
    f32x4 g1 = *(const f32x4*)(gw + lane * 8 + 4);
    f32x4 bb0 = *(const f32x4*)(bw + lane * 8);
    f32x4 bb1 = *(const f32x4*)(bw + lane * 8 + 4);
    f32x4 y0 = d0 * rstd * g0 + bb0;
    f32x4 y1 = d1 * rstd * g1 + bb1;
    *(f32x4*)(x32 + o) = y0;
    *(f32x4*)(x32 + o + 4) = y1;
    union { unsigned short s[8]; uint4 v; } pk;
    pk.s[0] = f2b(y0[0]); pk.s[1] = f2b(y0[1]); pk.s[2] = f2b(y0[2]); pk.s[3] = f2b(y0[3]);
    pk.s[4] = f2b(y1[0]); pk.s[5] = f2b(y1[1]); pk.s[6] = f2b(y1[2]); pk.s[7] = f2b(y1[3]);
    *(uint4*)((unsigned short*)xbf + o) = pk.v;
}

// ---------------- final: out[b,:] = x32[b*S + 0, :] --------------------------
__global__ __launch_bounds__(256)
void out_kernel(const float* __restrict__ x32, float* __restrict__ out) {
    int i = blockIdx.x * 256 + threadIdx.x;
    int b = i >> 9, e = i & 511;
    out[i] = x32[(size_t)b * S_ * E_ + e];
}

extern "C" void kernel_launch(void* const* d_in, const int* in_sizes, int n_in,
                              void* d_out, int out_size, void* d_ws, size_t ws_size,
                              hipStream_t stream) {
    (void)in_sizes; (void)n_in; (void)out_size; (void)ws_size;
    const int*   token_type = (const int*)d_in[0];
    const int*   mask       = (const int*)d_in[1];
    const int*   dec_idx    = (const int*)d_in[2];
    const float* action_val = (const float*)d_in[3];
    const float* dis_val    = (const float*)d_in[4];
    const float* v_val      = (const float*)d_in[5];
    const float* action_W   = (const float*)d_in[6];
    const float* action_b   = (const float*)d_in[7];
    const float* dis_W      = (const float*)d_in[8];
    const float* dis_b      = (const float*)d_in[9];
    const float* v_W        = (const float*)d_in[10];
    const float* v_b        = (const float*)d_in[11];
    const float* dec_emb    = (const float*)d_in[12];
    const float* pos        = (const float*)d_in[13];
    const float* cls        = (const float*)d_in[14];
    const float* qkv_W      = (const float*)d_in[15];
    const float* qkv_b      = (const float*)d_in[16];
    const float* out_W      = (const float*)d_in[17];
    const float* out_b      = (const float*)d_in[18];
    const float* ln1_g      = (const float*)d_in[19];
    const float* ln1_b      = (const float*)d_in[20];
    const float* ff1_W      = (const float*)d_in[21];
    const float* ff1_b      = (const float*)d_in[22];
    const float* ff2_W      = (const float*)d_in[23];
    const float* ff2_b      = (const float*)d_in[24];
    const float* ln2_g      = (const float*)d_in[25];
    const float* ln2_b      = (const float*)d_in[26];

    char* ws = (char*)d_ws;
    size_t off = 0;
    auto alloc = [&](size_t bytes) {
        char* p = ws + off;
        off += (bytes + 255) & ~(size_t)255;
        return p;
    };
    bf16* qkvT = (bf16*)alloc((size_t)L_ * 1536 * 512 * 2);  //  9.4 MB
    bf16* outT = (bf16*)alloc((size_t)L_ * 512 * 512 * 2);   //  3.1 MB
    bf16* ff1T = (bf16*)alloc((size_t)L_ * 2048 * 512 * 2);  // 12.6 MB
    bf16* ff2T = (bf16*)alloc((size_t)L_ * 512 * 2048 * 2);  // 12.6 MB
    float* x32 = (float*)alloc((size_t)M_ * E_ * 4);         // 79.2 MB residual (f32)
    bf16*  xbf = (bf16*)alloc((size_t)M_ * E_ * 2);          // 39.6 MB x(bf16)
    char*  arena = alloc((size_t)M_ * E_ * 4);               // 79.2 MB shared scratch
    // arena roles (sequential lifetimes):
    //   qkv half-chunk: 19328*1536*2 = 59.4 MB
    //   proj out (bf16): 38656*512*2 = 39.6 MB
    //   ff half-chunk hbf: 19328*2048*2 = 79.17 MB  (ff2 writes into xbf in-place)

    dim3 blk(256);
    transpose_cast_kernel<<<dim3(8, 24, L_), blk, 0, stream>>>(qkv_W, qkvT, 512, 1536);
    transpose_cast_kernel<<<dim3(8, 8,  L_), blk, 0, stream>>>(out_W, outT, 512, 512);
    transpose_cast_kernel<<<dim3(8, 32, L_), blk, 0, stream>>>(ff1_W, ff1T, 512, 2048);
    transpose_cast_kernel<<<dim3(32, 8, L_), blk, 0, stream>>>(ff2_W, ff2T, 2048, 512);

    embed_kernel<<<dim3(M_ / 4), blk, 0, stream>>>(token_type, dec_idx, action_val, dis_val, v_val,
        action_W, action_b, dis_W, dis_b, v_W, v_b, dec_emb, pos, cls, x32, xbf);

    const int HALF_ROWS = 19328;                 // 151 tiles * 128 rows

    for (int l = 0; l < L_; ++l) {
        const bf16* qT = qkvT + (size_t)l * 1536 * 512;
        const bf16* oT = outT + (size_t)l * 512 * 512;
        const bf16* f1 = ff1T + (size_t)l * 2048 * 512;
        const bf16* f2 = ff2T + (size_t)l * 512 * 2048;

        // QKV + attention, chunked over 2 batch-halves (arena = qkv chunk)
        for (int c = 0; c < 2; ++c) {
            gemm_kernel<3><<<dim3(151 * 12), blk, 0, stream>>>(
                xbf + (size_t)c * HALF_ROWS * E_, qT, qkv_b + l * 1536,
                (bf16*)arena, 1536, 512);
            attn_kernel<<<dim3(128 * H_), blk, 0, stream>>>(
                (const bf16*)arena, mask + c * 128 * T_,
                xbf + (size_t)c * HALF_ROWS * E_);   // attn-out overwrites xbf
        }
        // proj (bf16 out) -> arena, then fused res+LN1
        gemm_kernel<3><<<dim3(302 * 4), blk, 0, stream>>>(
            xbf, oT, out_b + l * 512, (bf16*)arena, 512, 512);
        ln_res_kernel<<<dim3(M_ / 4), blk, 0, stream>>>(
            (const bf16*)arena, ln1_g + l * 512, ln1_b + l * 512, x32, xbf);
        // FF, 2 half-chunks: ff1 -> arena (79.17MB), ff2 -> xbf in-place
        for (int c = 0; c < 2; ++c) {
            size_t rb = (size_t)c * HALF_ROWS;
            gemm_kernel<1><<<dim3(151 * 16), blk, 0, stream>>>(
                xbf + rb * E_, f1, ff1_b + l * 2048,
                (bf16*)arena, 2048, 512);
            gemm_kernel<3><<<dim3(151 * 4), blk, 0, stream>>>(
                (const bf16*)arena, f2, ff2_b + l * 512,
                xbf + rb * E_, 512, 2048);
            ln_res_kernel<<<dim3(HALF_ROWS / 4), blk, 0, stream>>>(
                xbf + rb * E_, ln2_g + l * 512, ln2_b + l * 512,
                x32 + rb * E_, xbf + rb * E_);
        }
    }
    out_kernel<<<dim3(B_ * E_ / 256), blk, 0, stream>>>(x32, (float*)d_out);
}